// Round 4
// baseline (705.154 us; speedup 1.0000x reference)
//
#include <hip/hip_runtime.h>
#include <hip/hip_bf16.h>

#define T_TOK 1024
#define H_DIM 2048
#define NH 16
#define NKV 4
#define HD 128
#define NEXP 8
#define I_DIM 768
#define EPSF 1e-6f

typedef unsigned short ushort_t;
typedef __attribute__((ext_vector_type(8))) _Float16 half8;
typedef __attribute__((ext_vector_type(4))) float f32x4;
typedef __attribute__((ext_vector_type(4))) unsigned short us4;

__device__ __forceinline__ ushort_t f2h(float x) {
    _Float16 h = (_Float16)x;
    return __builtin_bit_cast(ushort_t, h);
}
__device__ __forceinline__ float h2f_(ushort_t u) {
    return (float)__builtin_bit_cast(_Float16, u);
}
__device__ __forceinline__ void gld16(const ushort_t* g, ushort_t* l) {
    __builtin_amdgcn_global_load_lds(
        (const __attribute__((address_space(1))) unsigned int*)g,
        (__attribute__((address_space(3))) unsigned int*)l, 16, 0, 0);
}

// ---------------- residual add + RMSNorm -> res f32, h as f16 hi/lo planes ----------------
__global__ __launch_bounds__(256) void add_rms1(const float* __restrict__ a,
                                                const float* __restrict__ b,
                                                const float* __restrict__ w,
                                                float* __restrict__ res,
                                                ushort_t* __restrict__ hh,
                                                ushort_t* __restrict__ hl) {
    int t = blockIdx.x, tid = threadIdx.x;
    float v[8];
    float ss = 0.f;
#pragma unroll
    for (int i = 0; i < 8; i++) {
        int idx = t * H_DIM + tid + i * 256;
        v[i] = a[idx] + b[idx];
        res[idx] = v[i];
        ss += v[i] * v[i];
    }
#pragma unroll
    for (int o = 32; o; o >>= 1) ss += __shfl_down(ss, o);
    __shared__ float red[4];
    if ((tid & 63) == 0) red[tid >> 6] = ss;
    __syncthreads();
    float tot = red[0] + red[1] + red[2] + red[3];
    float scale = rsqrtf(tot / (float)H_DIM + EPSF);
#pragma unroll
    for (int i = 0; i < 8; i++) {
        int c = tid + i * 256;
        float hv = v[i] * scale * w[c];
        ushort_t hi = f2h(hv);
        hh[t * H_DIM + c] = hi;
        hl[t * H_DIM + c] = f2h(hv - h2f_(hi));
    }
}

// ------- residual add + RMSNorm, 2 partial inputs (split-K oproj) -> res f32, h f32, h f16 -------
__global__ __launch_bounds__(256) void add_rms2(const float* __restrict__ a0,
                                                const float* __restrict__ a1,
                                                const float* __restrict__ b,
                                                const float* __restrict__ w,
                                                float* __restrict__ res,
                                                float* __restrict__ hf,
                                                ushort_t* __restrict__ hh) {
    int t = blockIdx.x, tid = threadIdx.x;
    float v[8];
    float ss = 0.f;
#pragma unroll
    for (int i = 0; i < 8; i++) {
        int idx = t * H_DIM + tid + i * 256;
        v[i] = a0[idx] + a1[idx] + b[idx];
        res[idx] = v[i];
        ss += v[i] * v[i];
    }
#pragma unroll
    for (int o = 32; o; o >>= 1) ss += __shfl_down(ss, o);
    __shared__ float red[4];
    if ((tid & 63) == 0) red[tid >> 6] = ss;
    __syncthreads();
    float tot = red[0] + red[1] + red[2] + red[3];
    float scale = rsqrtf(tot / (float)H_DIM + EPSF);
#pragma unroll
    for (int i = 0; i < 8; i++) {
        int c = tid + i * 256;
        float hv = v[i] * scale * w[c];
        hf[t * H_DIM + c] = hv;
        hh[t * H_DIM + c] = f2h(hv);
    }
}

// ---------------- cast+transpose f32 [R][C(ld)] -> f16 hi/lo [C][R] ----------------
__global__ __launch_bounds__(256) void castT_hl(const float* __restrict__ in,
                                                ushort_t* __restrict__ oh,
                                                ushort_t* __restrict__ ol,
                                                int R, int ld) {
    __shared__ float tile[32][33];
    int r0 = blockIdx.y * 32, c0 = blockIdx.x * 32;
    int tx = threadIdx.x & 31, ty = threadIdx.x >> 5;
#pragma unroll
    for (int i = 0; i < 4; i++)
        tile[ty + 8 * i][tx] = in[(size_t)(r0 + ty + 8 * i) * ld + c0 + tx];
    __syncthreads();
#pragma unroll
    for (int i = 0; i < 4; i++) {
        float v = tile[tx][ty + 8 * i];
        ushort_t hi = f2h(v);
        size_t idx = (size_t)(c0 + ty + 8 * i) * R + r0 + tx;
        oh[idx] = hi;
        ol[idx] = f2h(v - h2f_(hi));
    }
}

// ---------------- cast+transpose f32 [R][C(ld)] -> f16 [C][R], z-batched ----------------
__global__ __launch_bounds__(256) void castT_h(const float* __restrict__ in,
                                               ushort_t* __restrict__ out,
                                               int R, int ld, size_t zstride) {
    in += (size_t)blockIdx.z * zstride;
    out += (size_t)blockIdx.z * zstride;
    __shared__ float tile[32][33];
    int r0 = blockIdx.y * 32, c0 = blockIdx.x * 32;
    int tx = threadIdx.x & 31, ty = threadIdx.x >> 5;
#pragma unroll
    for (int i = 0; i < 4; i++)
        tile[ty + 8 * i][tx] = in[(size_t)(r0 + ty + 8 * i) * ld + c0 + tx];
    __syncthreads();
#pragma unroll
    for (int i = 0; i < 4; i++)
        out[(size_t)(c0 + ty + 8 * i) * R + r0 + tx] = f2h(tile[tx][ty + 8 * i]);
}

// ---------------- V transpose+cast: qkv f32 V region -> Vt hi/lo planes [g][128][1024] ----------------
__global__ __launch_bounds__(256) void prep_vt(const float* __restrict__ qkv,
                                               ushort_t* __restrict__ vh,
                                               ushort_t* __restrict__ vl) {
    __shared__ float tile[32][33];
    int g = blockIdx.z;
    int t0 = blockIdx.y * 32, d0 = blockIdx.x * 32;
    int tx = threadIdx.x & 31, ty = threadIdx.x >> 5;
#pragma unroll
    for (int i = 0; i < 4; i++)
        tile[ty + 8 * i][tx] = qkv[(size_t)(t0 + ty + 8 * i) * 3072 + 2560 + g * HD + d0 + tx];
    __syncthreads();
#pragma unroll
    for (int i = 0; i < 4; i++) {
        float v = tile[tx][ty + 8 * i];
        ushort_t hi = f2h(v);
        size_t idx = (size_t)(g * HD + d0 + ty + 8 * i) * T_TOK + t0 + tx;
        vh[idx] = hi;
        vl[idx] = f2h(v - h2f_(hi));
    }
}

// ------- split-f16 MFMA GEMM, split-K: zpart==0 -> atomic accumulate into zeroed C;
//         zpart>0 -> each z writes its own partial at C + z*zpart*ldc -------
__global__ __launch_bounds__(256) void gemm_f16x3(const ushort_t* __restrict__ Ah,
                                                  const ushort_t* __restrict__ Al_,
                                                  const ushort_t* __restrict__ Bh,
                                                  const ushort_t* __restrict__ Bl_,
                                                  float* __restrict__ C,
                                                  int ldc, int K, int zpart) {
    __shared__ ushort_t sAh[4096], sAl[4096], sBh[4096], sBl[4096];
    int tid = threadIdx.x, lane = tid & 63, wv = tid >> 6;
    int m0 = blockIdx.y * 128, n0 = blockIdx.x * 128;
    int Kc = K / gridDim.z;
    int kz = blockIdx.z * Kc;
    int wm = (wv & 1) * 64, wn = (wv >> 1) * 64;
    int fr = lane & 15, fq = lane >> 4;
    f32x4 acc[4][4];
#pragma unroll
    for (int i = 0; i < 4; i++)
#pragma unroll
        for (int j = 0; j < 4; j++) acc[i][j] = {0.f, 0.f, 0.f, 0.f};

    size_t aoff = (size_t)(m0 + wv * 32 + (lane >> 2)) * K + (lane & 3) * 8 + kz;
    size_t boff = (size_t)(n0 + wv * 32 + (lane >> 2)) * K + (lane & 3) * 8 + kz;
    const ushort_t* gAh = Ah + aoff;
    const ushort_t* gAl = Al_ + aoff;
    const ushort_t* gBh = Bh + boff;
    const ushort_t* gBl = Bl_ + boff;

    for (int k0 = 0; k0 < Kc; k0 += 32) {
        gld16(gAh, &sAh[(wv * 32) * 32]);
        gld16(gAh + (size_t)16 * K, &sAh[(wv * 32 + 16) * 32]);
        gld16(gAl, &sAl[(wv * 32) * 32]);
        gld16(gAl + (size_t)16 * K, &sAl[(wv * 32 + 16) * 32]);
        gld16(gBh, &sBh[(wv * 32) * 32]);
        gld16(gBh + (size_t)16 * K, &sBh[(wv * 32 + 16) * 32]);
        gld16(gBl, &sBl[(wv * 32) * 32]);
        gld16(gBl + (size_t)16 * K, &sBl[(wv * 32 + 16) * 32]);
        gAh += 32; gAl += 32; gBh += 32; gBl += 32;
        __syncthreads();
        half8 ah[4], al[4], bh[4], bl[4];
#pragma unroll
        for (int i = 0; i < 4; i++) {
            int off = (wm + i * 16 + fr) * 32 + fq * 8;
            ah[i] = *(const half8*)&sAh[off];
            al[i] = *(const half8*)&sAl[off];
        }
#pragma unroll
        for (int j = 0; j < 4; j++) {
            int off = (wn + j * 16 + fr) * 32 + fq * 8;
            bh[j] = *(const half8*)&sBh[off];
            bl[j] = *(const half8*)&sBl[off];
        }
#pragma unroll
        for (int i = 0; i < 4; i++)
#pragma unroll
            for (int j = 0; j < 4; j++) {
                acc[i][j] = __builtin_amdgcn_mfma_f32_16x16x32_f16(ah[i], bh[j], acc[i][j], 0, 0, 0);
                acc[i][j] = __builtin_amdgcn_mfma_f32_16x16x32_f16(ah[i], bl[j], acc[i][j], 0, 0, 0);
                acc[i][j] = __builtin_amdgcn_mfma_f32_16x16x32_f16(al[i], bh[j], acc[i][j], 0, 0, 0);
            }
        __syncthreads();
    }
    float* Cw = C + (size_t)blockIdx.z * (size_t)zpart * (size_t)ldc;
#pragma unroll
    for (int i = 0; i < 4; i++)
#pragma unroll
        for (int j = 0; j < 4; j++)
#pragma unroll
            for (int r = 0; r < 4; r++) {
                int row = m0 + wm + i * 16 + fq * 4 + r;
                int col = n0 + wn + j * 16 + fr;
                if (zpart)
                    Cw[(size_t)row * ldc + col] = acc[i][j][r];
                else
                    atomicAdd(&C[(size_t)row * ldc + col], acc[i][j][r]);
            }
}

// ---------------- grouped f16 MFMA GEMM (MoE): gathered A rows, scattered C rows ----------------
__global__ __launch_bounds__(256) void moe_gemm(const ushort_t* __restrict__ Ab,
                                                const ushort_t* __restrict__ BtAll,
                                                const int* __restrict__ cnt,
                                                const int* __restrict__ ridx_g,
                                                const int* __restrict__ oidx_g,
                                                ushort_t* __restrict__ Cout,
                                                int N, int K, int ebase) {
    int e = ebase + blockIdx.z;
    int nt = cnt[e];
    int mt0 = blockIdx.y * 128;
    if (mt0 >= nt) return;
    const ushort_t* Bt = BtAll + (size_t)blockIdx.z * N * K;
    int n0 = blockIdx.x * 128;
    __shared__ ushort_t Al[4096];
    __shared__ ushort_t Bl[4096];
    __shared__ int ridx[128], oidx[128];
    int tid = threadIdx.x, lane = tid & 63, wv = tid >> 6;
    if (tid < 128) {
        int ii = mt0 + tid;
        bool v = ii < nt;
        ridx[tid] = v ? ridx_g[e * T_TOK + ii] : -1;
        oidx[tid] = v ? oidx_g[e * T_TOK + ii] : -1;
    }
    __syncthreads();
    int wm = (wv & 1) * 64, wn = (wv >> 1) * 64;
    int fr = lane & 15, fq = lane >> 4;
    f32x4 acc[4][4];
#pragma unroll
    for (int i = 0; i < 4; i++)
#pragma unroll
        for (int j = 0; j < 4; j++) acc[i][j] = {0.f, 0.f, 0.f, 0.f};

    int arow = tid >> 1, akoff = (tid & 1) * 16;
    int ra = ridx[arow];
    const ushort_t* asrc = (ra >= 0) ? (Ab + (size_t)ra * K + akoff) : (const ushort_t*)0;
    const ushort_t* gB = Bt + (size_t)(n0 + wv * 32 + (lane >> 2)) * K + (lane & 3) * 8;

    for (int k0 = 0; k0 < K; k0 += 32) {
        uint4 v0 = {0, 0, 0, 0}, v1 = {0, 0, 0, 0};
        if (ra >= 0) {
            v0 = *(const uint4*)(asrc);
            v1 = *(const uint4*)(asrc + 8);
            asrc += 32;
        }
        gld16(gB, &Bl[(wv * 32) * 32]);
        gld16(gB + (size_t)16 * K, &Bl[(wv * 32 + 16) * 32]);
        gB += 32;
        *(uint4*)&Al[arow * 32 + akoff] = v0;
        *(uint4*)&Al[arow * 32 + akoff + 8] = v1;
        __syncthreads();
        half8 af[4], bfr[4];
#pragma unroll
        for (int i = 0; i < 4; i++) af[i] = *(const half8*)&Al[(wm + i * 16 + fr) * 32 + fq * 8];
#pragma unroll
        for (int j = 0; j < 4; j++) bfr[j] = *(const half8*)&Bl[(wn + j * 16 + fr) * 32 + fq * 8];
#pragma unroll
        for (int i = 0; i < 4; i++)
#pragma unroll
            for (int j = 0; j < 4; j++)
                acc[i][j] = __builtin_amdgcn_mfma_f32_16x16x32_f16(af[i], bfr[j], acc[i][j], 0, 0, 0);
        __syncthreads();
    }
#pragma unroll
    for (int i = 0; i < 4; i++)
#pragma unroll
        for (int j = 0; j < 4; j++)
#pragma unroll
            for (int r = 0; r < 4; r++) {
                int lr = wm + i * 16 + fq * 4 + r;
                if (mt0 + lr < nt) {
                    int orow = oidx[lr];
                    Cout[(size_t)orow * N + n0 + wn + j * 16 + fr] = f2h(acc[i][j][r]);
                }
            }
}

// ------- QK RMSNorm + neox RoPE; writes Q and K directly as f16 hi/lo planes -------
// Q planes: [t][NH*128]; K planes: [t][NKV*128]
__global__ __launch_bounds__(128) void qk_rope_prep(const float* __restrict__ qkv,
                                                    const float* __restrict__ qw,
                                                    const float* __restrict__ kw,
                                                    const int* __restrict__ positions,
                                                    ushort_t* __restrict__ Qhp,
                                                    ushort_t* __restrict__ Qlp,
                                                    ushort_t* __restrict__ Khp,
                                                    ushort_t* __restrict__ Klp) {
    int t = blockIdx.x / (NH + NKV);
    int hh = blockIdx.x % (NH + NKV);
    bool isq = hh < NH;
    const float* x = isq ? qkv + (size_t)t * 3072 + hh * HD
                         : qkv + (size_t)t * 3072 + 2048 + (hh - NH) * HD;
    const float* w = isq ? qw : kw;
    int tid = threadIdx.x;
    float v = x[tid];
    float ss = v * v;
#pragma unroll
    for (int o = 32; o; o >>= 1) ss += __shfl_down(ss, o);
    __shared__ float red[2];
    if ((tid & 63) == 0) red[tid >> 6] = ss;
    __syncthreads();
    float tot = red[0] + red[1];
    float scale = rsqrtf(tot / (float)HD + EPSF);
    float xn = v * scale * w[tid];
    __shared__ float buf[HD];
    buf[tid] = xn;
    __syncthreads();
    if (tid < 64) {
        float x1 = buf[tid], x2 = buf[tid + 64];
        float invf = expf(-((float)tid / 64.0f) * logf(1000000.0f));
        float ang = (float)positions[t] * invf;
        float c = cosf(ang), s = sinf(ang);
        float xa = x1 * c - x2 * s;
        float xb = x2 * c + x1 * s;
        size_t base = isq ? ((size_t)t * (NH * HD) + hh * HD)
                          : ((size_t)t * (NKV * HD) + (hh - NH) * HD);
        ushort_t* oh = isq ? Qhp : Khp;
        ushort_t* ol = isq ? Qlp : Klp;
        ushort_t ha = f2h(xa);
        oh[base + tid] = ha;
        ol[base + tid] = f2h(xa - h2f_(ha));
        ushort_t hb = f2h(xb);
        oh[base + tid + 64] = hb;
        ol[base + tid + 64] = f2h(xb - h2f_(hb));
    }
}

// ---------------- MFMA flash attention: preconverted f16 hi/lo planes, async reg prefetch ----------------
// block = 256 threads (4 waves), one block per (64-query tile, head).
// K/V for tile kt+1 are loaded to registers while tile kt computes (T14 split).
#define ATT_SCALE 0.08838834764831845f
__global__ __launch_bounds__(256) void attn_mfma(const ushort_t* __restrict__ Qhp,
                                                 const ushort_t* __restrict__ Qlp,
                                                 const ushort_t* __restrict__ Khp,
                                                 const ushort_t* __restrict__ Klp,
                                                 const ushort_t* __restrict__ Vthp,
                                                 const ushort_t* __restrict__ Vtlp,
                                                 ushort_t* __restrict__ ohp,
                                                 ushort_t* __restrict__ olp) {
    __shared__ _Float16 sKh[64 * 136], sKl[64 * 136];   // K rows, padded stride 136
    __shared__ _Float16 sVh[128 * 72], sVl[128 * 72];   // Vt rows [d][krow], padded stride 72
    __shared__ _Float16 sPh[64 * 72], sPl[64 * 72];     // P [qrow][krow]

    int qi = blockIdx.x, h = blockIdx.y;
    int q0 = qi * 64, g = h >> 2;
    int tid = threadIdx.x, lane = tid & 63, wv = tid >> 6;
    int quad = lane >> 4, n16 = lane & 15;

    // ---- Q A-frags direct from global planes (once per block) ----
    half8 qh[4], ql[4];
#pragma unroll
    for (int ks = 0; ks < 4; ks++) {
        size_t off = (size_t)(q0 + wv * 16 + n16) * (NH * HD) + h * HD + ks * 32 + quad * 8;
        qh[ks] = *(const half8*)&Qhp[off];
        ql[ks] = *(const half8*)&Qlp[off];
    }

    // staging registers for one K/V tile (16 x b128)
    uint4 rkh[4], rkl[4], rvh[4], rvl[4];

#define STAGE_LOAD(K0)                                                             \
    {                                                                              \
        _Pragma("unroll") for (int i = 0; i < 4; i++) {                            \
            int ch = tid + 256 * i;                                                \
            int row = ch >> 4, c8 = ch & 15;                                       \
            size_t go = (size_t)((K0) + row) * (NKV * HD) + g * HD + c8 * 8;       \
            rkh[i] = *(const uint4*)&Khp[go];                                      \
            rkl[i] = *(const uint4*)&Klp[go];                                      \
        }                                                                          \
        _Pragma("unroll") for (int i = 0; i < 4; i++) {                            \
            int ch = tid + 256 * i;                                                \
            int d = ch >> 3, c8 = ch & 7;                                          \
            size_t go = (size_t)(g * HD + d) * T_TOK + (K0) + c8 * 8;              \
            rvh[i] = *(const uint4*)&Vthp[go];                                     \
            rvl[i] = *(const uint4*)&Vtlp[go];                                     \
        }                                                                          \
    }

#define STAGE_WRITE()                                                              \
    {                                                                              \
        _Pragma("unroll") for (int i = 0; i < 4; i++) {                            \
            int ch = tid + 256 * i;                                                \
            int row = ch >> 4, c8 = ch & 15;                                       \
            *(uint4*)&sKh[row * 136 + c8 * 8] = rkh[i];                            \
            *(uint4*)&sKl[row * 136 + c8 * 8] = rkl[i];                            \
        }                                                                          \
        _Pragma("unroll") for (int i = 0; i < 4; i++) {                            \
            int ch = tid + 256 * i;                                                \
            int d = ch >> 3, c8 = ch & 7;                                          \
            *(uint4*)&sVh[d * 72 + c8 * 8] = rvh[i];                               \
            *(uint4*)&sVl[d * 72 + c8 * 8] = rvl[i];                               \
        }                                                                          \
    }

    float m_r[4], l_r[4];
#pragma unroll
    for (int r = 0; r < 4; r++) { m_r[r] = -1e30f; l_r[r] = 0.f; }
    f32x4 acc[8];
#pragma unroll
    for (int d = 0; d < 8; d++) acc[d] = {0.f, 0.f, 0.f, 0.f};

    // prologue: stage tile 0
    STAGE_LOAD(0);
    STAGE_WRITE();
    __syncthreads();

    for (int kt = 0; kt <= qi; kt++) {
        // issue next tile's global loads early (latency hides under compute)
        if (kt < qi) STAGE_LOAD((kt + 1) * 64);

        // ---- S = Q K^T : per wave 16q x 64k, hi*hi + hi*lo + lo*hi ----
        f32x4 s[4];
#pragma unroll
        for (int jt = 0; jt < 4; jt++) s[jt] = {0.f, 0.f, 0.f, 0.f};
#pragma unroll
        for (int ks = 0; ks < 4; ks++)
#pragma unroll
            for (int jt = 0; jt < 4; jt++) {
                int off = (jt * 16 + n16) * 136 + ks * 32 + quad * 8;
                half8 bh = *(const half8*)&sKh[off];
                half8 bl = *(const half8*)&sKl[off];
                s[jt] = __builtin_amdgcn_mfma_f32_16x16x32_f16(qh[ks], bh, s[jt], 0, 0, 0);
                s[jt] = __builtin_amdgcn_mfma_f32_16x16x32_f16(qh[ks], bl, s[jt], 0, 0, 0);
                s[jt] = __builtin_amdgcn_mfma_f32_16x16x32_f16(ql[ks], bh, s[jt], 0, 0, 0);
            }

        // ---- online softmax in C-layout (row = quad*4+r, col = jt*16+n16) ----
        bool last = (kt == qi);
        int lrow_base = wv * 16 + quad * 4;
#pragma unroll
        for (int r = 0; r < 4; r++) {
            float rm = -1e30f;
#pragma unroll
            for (int jt = 0; jt < 4; jt++) {
                float sv = s[jt][r] * ATT_SCALE;
                if (last && (jt * 16 + n16 > lrow_base + r)) sv = -1e30f;
                s[jt][r] = sv;
                rm = fmaxf(rm, sv);
            }
            rm = fmaxf(rm, __shfl_xor(rm, 1));
            rm = fmaxf(rm, __shfl_xor(rm, 2));
            rm = fmaxf(rm, __shfl_xor(rm, 4));
            rm = fmaxf(rm, __shfl_xor(rm, 8));
            float mo = m_r[r], mn = fmaxf(mo, rm);
            float al = __expf(mo - mn);
            float ls = 0.f;
#pragma unroll
            for (int jt = 0; jt < 4; jt++) {
                float p = __expf(s[jt][r] - mn);
                ls += p;
                _Float16 phi = (_Float16)p;
                int poff = (lrow_base + r) * 72 + jt * 16 + n16;
                sPh[poff] = phi;
                sPl[poff] = (_Float16)(p - (float)phi);
            }
            ls += __shfl_xor(ls, 1);
            ls += __shfl_xor(ls, 2);
            ls += __shfl_xor(ls, 4);
            ls += __shfl_xor(ls, 8);
            l_r[r] = l_r[r] * al + ls;
            m_r[r] = mn;
#pragma unroll
            for (int dt = 0; dt < 8; dt++) acc[dt][r] *= al;
        }
        __syncthreads();  // P visible; K fully consumed

        // ---- PV: P (A via LDS round-trip) x V (B from transposed Vt) ----
        half8 pah[2], pal[2];
#pragma unroll
        for (int ks = 0; ks < 2; ks++) {
            int off = (wv * 16 + n16) * 72 + ks * 32 + quad * 8;
            pah[ks] = *(const half8*)&sPh[off];
            pal[ks] = *(const half8*)&sPl[off];
        }
#pragma unroll
        for (int dt = 0; dt < 8; dt++)
#pragma unroll
            for (int ks = 0; ks < 2; ks++) {
                int off = (dt * 16 + n16) * 72 + ks * 32 + quad * 8;
                half8 vh = *(const half8*)&sVh[off];
                half8 vl = *(const half8*)&sVl[off];
                acc[dt] = __builtin_amdgcn_mfma_f32_16x16x32_f16(pah[ks], vh, acc[dt], 0, 0, 0);
                acc[dt] = __builtin_amdgcn_mfma_f32_16x16x32_f16(pah[ks], vl, acc[dt], 0, 0, 0);
                acc[dt] = __builtin_amdgcn_mfma_f32_16x16x32_f16(pal[ks], vh, acc[dt], 0, 0, 0);
            }
        __syncthreads();  // V and P consumed

        if (kt < qi) {
            STAGE_WRITE();   // compiler inserts vmcnt wait before first reg use
            __syncthreads();
        }
    }

    // ---- epilogue: o = acc / l, written as f16 hi/lo planes ----
#pragma unroll
    for (int r = 0; r < 4; r++) {
        float inv = 1.f / l_r[r];
        int row = q0 + wv * 16 + quad * 4 + r;
#pragma unroll
        for (int dt = 0; dt < 8; dt++) {
            float val = acc[dt][r] * inv;
            _Float16 hi = (_Float16)val;
            size_t idx = (size_t)row * 2048 + h * HD + dt * 16 + n16;
            ohp[idx] = __builtin_bit_cast(ushort_t, hi);
            olp[idx] = __builtin_bit_cast(ushort_t, (_Float16)(val - (float)hi));
        }
    }
#undef STAGE_LOAD
#undef STAGE_WRITE
}

// ---------------- router: softmax over 8 experts, top-2, bucket by expert ----------------
__global__ __launch_bounds__(256) void router(const float* __restrict__ h2,
                                              const float* __restrict__ gate_w,
                                              int* __restrict__ cnt,
                                              int* __restrict__ btok,
                                              int* __restrict__ bslot,
                                              float* __restrict__ wslot) {
    int t = blockIdx.x, tid = threadIdx.x;
    int e = tid & 7, c = tid >> 3;
    float part = 0.f;
    for (int i = 0; i < 64; i++) {
        int hh = c * 64 + i;
        part += h2[(size_t)t * H_DIM + hh] * gate_w[hh * NEXP + e];
    }
    __shared__ float red[256];
    red[tid] = part;
    __syncthreads();
    for (int s = 128; s >= 8; s >>= 1) {
        if (tid < s) red[tid] += red[tid + s];
        __syncthreads();
    }
    if (tid == 0) {
        float mx = -1e30f;
        for (int i = 0; i < NEXP; i++) mx = fmaxf(mx, red[i]);
        float p[NEXP];
        for (int i = 0; i < NEXP; i++) p[i] = expf(red[i] - mx);
        int i1 = 0;
        for (int i = 1; i < NEXP; i++) if (p[i] > p[i1]) i1 = i;
        int i2 = (i1 == 0) ? 1 : 0;
        for (int i = 0; i < NEXP; i++) if (i != i1 && p[i] > p[i2]) i2 = i;
        float denom = p[i1] + p[i2];
        wslot[2 * t] = p[i1] / denom;
        wslot[2 * t + 1] = p[i2] / denom;
        int pos = atomicAdd(&cnt[i1], 1);
        btok[i1 * T_TOK + pos] = t; bslot[i1 * T_TOK + pos] = 2 * t;
        pos = atomicAdd(&cnt[i2], 1);
        btok[i2 * T_TOK + pos] = t; bslot[i2 * T_TOK + pos] = 2 * t + 1;
    }
}

// ---------------- SwiGLU: gu f16 [2048][1536] -> act f16 [2048][768] ----------------
__global__ __launch_bounds__(256) void swiglu(const ushort_t* __restrict__ gu,
                                              ushort_t* __restrict__ act) {
    int idx = blockIdx.x * 256 + threadIdx.x;
    int s = idx / I_DIM, i = idx - s * I_DIM;
    float g = h2f_(gu[(size_t)s * (2 * I_DIM) + i]);
    float u = h2f_(gu[(size_t)s * (2 * I_DIM) + I_DIM + i]);
    act[idx] = f2h(g / (1.f + expf(-g)) * u);
}

// ---------------- combine: out[t] = w0*dbuf[2t] + w1*dbuf[2t+1] ----------------
__global__ __launch_bounds__(256) void combine(const ushort_t* __restrict__ dbuf,
                                               const float* __restrict__ wslot,
                                               float* __restrict__ out) {
    int idx = blockIdx.x * 256 + threadIdx.x;
    int t = idx >> 11;
    out[idx] = wslot[2 * t] * h2f_(dbuf[(size_t)(2 * t) * H_DIM + (idx & 2047)]) +
               wslot[2 * t + 1] * h2f_(dbuf[(size_t)(2 * t + 1) * H_DIM + (idx & 2047)]);
}

extern "C" void kernel_launch(void* const* d_in, const int* in_sizes, int n_in,
                              void* d_out, int out_size, void* d_ws, size_t ws_size,
                              hipStream_t stream) {
    const int* positions = (const int*)d_in[0];
    const float* hs = (const float*)d_in[1];
    const float* resid = (const float*)d_in[2];
    const float* w_qkv = (const float*)d_in[3];
    const float* w_o = (const float*)d_in[4];
    const float* q_norm_w = (const float*)d_in[5];
    const float* k_norm_w = (const float*)d_in[6];
    const float* ln1_w = (const float*)d_in[7];
    const float* ln2_w = (const float*)d_in[8];
    const float* gate_w = (const float*)d_in[9];
    const float* w_gu = (const float*)d_in[10];
    const float* w_dn = (const float*)d_in[11];

    float* out = (float*)d_out;
    float* res2 = out + (size_t)T_TOK * H_DIM;

    const size_t MB = 1ull << 20;
    char* W = (char*)d_ws;
    // ---- per-step disjointness-audited layout (fix for r2/r3 oprojf<->wTh race) ----
    // 0-8:   res1 (live 2-8) | gub 0-6 (live 10-11) | dbuf 0-8 (live 12-13)
    float*    res1   = (float*)(W + 0);
    ushort_t* gub    = (ushort_t*)(W + 0);
    ushort_t* dbuf   = (ushort_t*)(W + 0);
    // 8-16:  h1h 8-12 / h1l 12-16 (live 2-3) | ohp 8-12 / olp 12-16 (live 5-7)
    //        | h2h 8-12 (live 8-10) | actb 12-15 (live 11-12)
    ushort_t* h1h    = (ushort_t*)(W + 8 * MB);
    ushort_t* h1l    = (ushort_t*)(W + 12 * MB);
    ushort_t* ohp    = (ushort_t*)(W + 8 * MB);
    ushort_t* olp    = (ushort_t*)(W + 12 * MB);
    ushort_t* h2h    = (ushort_t*)(W + 8 * MB);
    ushort_t* actb   = (ushort_t*)(W + 12 * MB);
    // 16-28: qkvf (live 3-4) | wTh_o 16-24 / wTl_o 24-32 (live 6-7) | h2f 16-24 (live 8-9)
    //        | wTmoe 16-41.2 (live 10-12)
    float*    qkvf   = (float*)(W + 16 * MB);
    ushort_t* wTh_o  = (ushort_t*)(W + 16 * MB);
    ushort_t* wTl_o  = (ushort_t*)(W + 24 * MB);
    float*    h2f    = (float*)(W + 16 * MB);
    ushort_t* wTmoe  = (ushort_t*)(W + 16 * MB);
    // 28-40: qkv weight transposes 28-34/34-40 (live step 3) | attn planes 28-40 (live 4-5)
    ushort_t* wTh_q  = (ushort_t*)(W + 28 * MB);
    ushort_t* wTl_q  = (ushort_t*)(W + 34 * MB);
    ushort_t* Qhp    = (ushort_t*)(W + 28 * MB);  // 4 MiB
    ushort_t* Qlp    = (ushort_t*)(W + 32 * MB);  // 4 MiB
    ushort_t* Khp    = (ushort_t*)(W + 36 * MB);  // 1 MiB
    ushort_t* Klp    = (ushort_t*)(W + 37 * MB);  // 1 MiB
    ushort_t* Vthp   = (ushort_t*)(W + 38 * MB);  // 1 MiB
    ushort_t* Vtlp   = (ushort_t*)(W + 39 * MB);  // 1 MiB
    // 32-48: oproj partials 2x8 MiB (live 7-8; disjoint from wTh_o/wTl_o at 16-32)
    float*    oprojf = (float*)(W + 32 * MB);
    // 48+:   buckets (live 9-13)
    int*      cnt    = (int*)(W + 48 * MB);
    int*      btok   = cnt + 16;
    int*      bslot  = btok + NEXP * T_TOK;
    float*    wslot  = (float*)(bslot + NEXP * T_TOK);

    // 1+2. res1 = hs + resid; h1 = rms(res1)*ln1 as f16 hi/lo
    add_rms1<<<T_TOK, 256, 0, stream>>>(hs, resid, ln1_w, res1, h1h, h1l);
    // 3. qkv = h1 @ w_qkv in two N-chunks of 1536, split-K=4 (atomic f32)
    hipMemsetAsync(qkvf, 0, (size_t)T_TOK * 3072 * 4, stream);
    for (int c = 0; c < 2; c++) {
        castT_hl<<<dim3(1536 / 32, 2048 / 32), 256, 0, stream>>>(
            w_qkv + c * 1536, wTh_q, wTl_q, 2048, 3072);
        gemm_f16x3<<<dim3(1536 / 128, 1024 / 128, 4), 256, 0, stream>>>(
            h1h, h1l, wTh_q, wTl_q, qkvf + c * 1536, 3072, 2048, 0);
    }
    // 4. q/k RMSNorm + RoPE -> Q/K f16 hi/lo planes; V transpose -> Vt planes
    qk_rope_prep<<<T_TOK * (NH + NKV), 128, 0, stream>>>(qkvf, q_norm_w, k_norm_w, positions,
                                                         Qhp, Qlp, Khp, Klp);
    prep_vt<<<dim3(HD / 32, T_TOK / 32, NKV), 256, 0, stream>>>(qkvf, Vthp, Vtlp);
    // 5. MFMA flash attention (reads planes 28-40) -> ohp/olp at 8-16
    attn_mfma<<<dim3(T_TOK / 64, NH), 256, 0, stream>>>(Qhp, Qlp, Khp, Klp, Vthp, Vtlp, ohp, olp);
    // 6. w_o transpose hi/lo -> 16-32 (qkvf dead; planes untouched but dead after attn)
    castT_hl<<<dim3(2048 / 32, 2048 / 32), 256, 0, stream>>>(w_o, wTh_o, wTl_o, 2048, 2048);
    // 7. oproj = attn_out @ w_o, split-K=2 partial mode -> 32-48 (disjoint from all reads)
    gemm_f16x3<<<dim3(2048 / 128, 1024 / 128, 2), 256, 0, stream>>>(
        ohp, olp, wTh_o, wTl_o, oprojf, 2048, 2048, 1024);
    // 8. res2 = oproj0 + oproj1 + res1 (-> d_out); h2 f32 (16-24) + f16 (8-12)
    add_rms2<<<T_TOK, 256, 0, stream>>>(oprojf, oprojf + (size_t)1024 * 2048, res1, ln2_w,
                                        res2, h2f, h2h);
    // 9. router (f32 logits)
    hipMemsetAsync(cnt, 0, NEXP * sizeof(int), stream);
    router<<<T_TOK, 256, 0, stream>>>(h2f, gate_w, cnt, btok, bslot, wslot);
    // 10. MoE gate_up in 2 chunks of 4 experts (weights at 16+; gub at 0)
    for (int c = 0; c < 2; c++) {
        castT_h<<<dim3(1536 / 32, 2048 / 32, 4), 256, 0, stream>>>(
            w_gu + (size_t)c * 4 * 2048 * 1536, wTmoe, 2048, 1536, (size_t)2048 * 1536);
        moe_gemm<<<dim3(1536 / 128, 8, 4), 256, 0, stream>>>(
            h2h, wTmoe, cnt, btok, bslot, gub, 1536, 2048, c * 4);
    }
    // 11. SwiGLU: gub (0-6) -> actb (12-15)
    swiglu<<<(2048 * I_DIM) / 256, 256, 0, stream>>>(gub, actb);
    // 12. MoE down, all 8 experts (weights 16-40; actb 12-15; dbuf 0-8)
    castT_h<<<dim3(2048 / 32, 768 / 32, 8), 256, 0, stream>>>(
        w_dn, wTmoe, 768, 2048, (size_t)768 * 2048);
    moe_gemm<<<dim3(2048 / 128, 8, 8), 256, 0, stream>>>(
        actb, wTmoe, cnt, bslot, bslot, dbuf, 2048, 768, 0);
    // 13. weighted combine
    combine<<<(T_TOK * H_DIM) / 256, 256, 0, stream>>>(dbuf, wslot, out);
}

// Round 6
// 680.857 us; speedup vs baseline: 1.0357x; 1.0357x over previous
//
#include <hip/hip_runtime.h>
#include <hip/hip_bf16.h>

#define T_TOK 1024
#define H_DIM 2048
#define NH 16
#define NKV 4
#define HD 128
#define NEXP 8
#define I_DIM 768
#define EPSF 1e-6f

typedef unsigned short ushort_t;
typedef __attribute__((ext_vector_type(8))) _Float16 half8;
typedef __attribute__((ext_vector_type(4))) float f32x4;
typedef __attribute__((ext_vector_type(4))) unsigned short us4;

__device__ __forceinline__ ushort_t f2h(float x) {
    _Float16 h = (_Float16)x;
    return __builtin_bit_cast(ushort_t, h);
}
__device__ __forceinline__ float h2f_(ushort_t u) {
    return (float)__builtin_bit_cast(_Float16, u);
}
__device__ __forceinline__ void gld16(const ushort_t* g, ushort_t* l) {
    __builtin_amdgcn_global_load_lds(
        (const __attribute__((address_space(1))) unsigned int*)g,
        (__attribute__((address_space(3))) unsigned int*)l, 16, 0, 0);
}

// ---------------- residual add + RMSNorm -> res f32, h as f16 hi/lo planes ----------------
__global__ __launch_bounds__(256) void add_rms1(const float* __restrict__ a,
                                                const float* __restrict__ b,
                                                const float* __restrict__ w,
                                                float* __restrict__ res,
                                                ushort_t* __restrict__ hh,
                                                ushort_t* __restrict__ hl) {
    int t = blockIdx.x, tid = threadIdx.x;
    float v[8];
    float ss = 0.f;
#pragma unroll
    for (int i = 0; i < 8; i++) {
        int idx = t * H_DIM + tid + i * 256;
        v[i] = a[idx] + b[idx];
        res[idx] = v[i];
        ss += v[i] * v[i];
    }
#pragma unroll
    for (int o = 32; o; o >>= 1) ss += __shfl_down(ss, o);
    __shared__ float red[4];
    if ((tid & 63) == 0) red[tid >> 6] = ss;
    __syncthreads();
    float tot = red[0] + red[1] + red[2] + red[3];
    float scale = rsqrtf(tot / (float)H_DIM + EPSF);
#pragma unroll
    for (int i = 0; i < 8; i++) {
        int c = tid + i * 256;
        float hv = v[i] * scale * w[c];
        ushort_t hi = f2h(hv);
        hh[t * H_DIM + c] = hi;
        hl[t * H_DIM + c] = f2h(hv - h2f_(hi));
    }
}

// ------- residual add + RMSNorm, 2 partial inputs (split-K oproj) -> res f32, h f32, h f16 -------
__global__ __launch_bounds__(256) void add_rms2(const float* __restrict__ a0,
                                                const float* __restrict__ a1,
                                                const float* __restrict__ b,
                                                const float* __restrict__ w,
                                                float* __restrict__ res,
                                                float* __restrict__ hf,
                                                ushort_t* __restrict__ hh) {
    int t = blockIdx.x, tid = threadIdx.x;
    float v[8];
    float ss = 0.f;
#pragma unroll
    for (int i = 0; i < 8; i++) {
        int idx = t * H_DIM + tid + i * 256;
        v[i] = a0[idx] + a1[idx] + b[idx];
        res[idx] = v[i];
        ss += v[i] * v[i];
    }
#pragma unroll
    for (int o = 32; o; o >>= 1) ss += __shfl_down(ss, o);
    __shared__ float red[4];
    if ((tid & 63) == 0) red[tid >> 6] = ss;
    __syncthreads();
    float tot = red[0] + red[1] + red[2] + red[3];
    float scale = rsqrtf(tot / (float)H_DIM + EPSF);
#pragma unroll
    for (int i = 0; i < 8; i++) {
        int c = tid + i * 256;
        float hv = v[i] * scale * w[c];
        hf[t * H_DIM + c] = hv;
        hh[t * H_DIM + c] = f2h(hv);
    }
}

// ---------------- cast+transpose f32 [R][C(ld)] -> f16 hi/lo [C][R] ----------------
__global__ __launch_bounds__(256) void castT_hl(const float* __restrict__ in,
                                                ushort_t* __restrict__ oh,
                                                ushort_t* __restrict__ ol,
                                                int R, int ld) {
    __shared__ float tile[32][33];
    int r0 = blockIdx.y * 32, c0 = blockIdx.x * 32;
    int tx = threadIdx.x & 31, ty = threadIdx.x >> 5;
#pragma unroll
    for (int i = 0; i < 4; i++)
        tile[ty + 8 * i][tx] = in[(size_t)(r0 + ty + 8 * i) * ld + c0 + tx];
    __syncthreads();
#pragma unroll
    for (int i = 0; i < 4; i++) {
        float v = tile[tx][ty + 8 * i];
        ushort_t hi = f2h(v);
        size_t idx = (size_t)(c0 + ty + 8 * i) * R + r0 + tx;
        oh[idx] = hi;
        ol[idx] = f2h(v - h2f_(hi));
    }
}

// ---------------- cast+transpose f32 [R][C(ld)] -> f16 [C][R], z-batched ----------------
__global__ __launch_bounds__(256) void castT_h(const float* __restrict__ in,
                                               ushort_t* __restrict__ out,
                                               int R, int ld, size_t zstride) {
    in += (size_t)blockIdx.z * zstride;
    out += (size_t)blockIdx.z * zstride;
    __shared__ float tile[32][33];
    int r0 = blockIdx.y * 32, c0 = blockIdx.x * 32;
    int tx = threadIdx.x & 31, ty = threadIdx.x >> 5;
#pragma unroll
    for (int i = 0; i < 4; i++)
        tile[ty + 8 * i][tx] = in[(size_t)(r0 + ty + 8 * i) * ld + c0 + tx];
    __syncthreads();
#pragma unroll
    for (int i = 0; i < 4; i++)
        out[(size_t)(c0 + ty + 8 * i) * R + r0 + tx] = f2h(tile[tx][ty + 8 * i]);
}

// ---------------- V transpose+cast: qkv f32 V region -> Vt hi/lo planes [g][128][1024] ----------------
__global__ __launch_bounds__(256) void prep_vt(const float* __restrict__ qkv,
                                               ushort_t* __restrict__ vh,
                                               ushort_t* __restrict__ vl) {
    __shared__ float tile[32][33];
    int g = blockIdx.z;
    int t0 = blockIdx.y * 32, d0 = blockIdx.x * 32;
    int tx = threadIdx.x & 31, ty = threadIdx.x >> 5;
#pragma unroll
    for (int i = 0; i < 4; i++)
        tile[ty + 8 * i][tx] = qkv[(size_t)(t0 + ty + 8 * i) * 3072 + 2560 + g * HD + d0 + tx];
    __syncthreads();
#pragma unroll
    for (int i = 0; i < 4; i++) {
        float v = tile[tx][ty + 8 * i];
        ushort_t hi = f2h(v);
        size_t idx = (size_t)(g * HD + d0 + ty + 8 * i) * T_TOK + t0 + tx;
        vh[idx] = hi;
        vl[idx] = f2h(v - h2f_(hi));
    }
}

// ------- split-f16 MFMA GEMM, split-K: zpart==0 -> atomic accumulate into zeroed C;
//         zpart>0 -> each z writes its own partial at C + z*zpart*ldc -------
__global__ __launch_bounds__(256) void gemm_f16x3(const ushort_t* __restrict__ Ah,
                                                  const ushort_t* __restrict__ Al_,
                                                  const ushort_t* __restrict__ Bh,
                                                  const ushort_t* __restrict__ Bl_,
                                                  float* __restrict__ C,
                                                  int ldc, int K, int zpart) {
    __shared__ ushort_t sAh[4096], sAl[4096], sBh[4096], sBl[4096];
    int tid = threadIdx.x, lane = tid & 63, wv = tid >> 6;
    int m0 = blockIdx.y * 128, n0 = blockIdx.x * 128;
    int Kc = K / gridDim.z;
    int kz = blockIdx.z * Kc;
    int wm = (wv & 1) * 64, wn = (wv >> 1) * 64;
    int fr = lane & 15, fq = lane >> 4;
    f32x4 acc[4][4];
#pragma unroll
    for (int i = 0; i < 4; i++)
#pragma unroll
        for (int j = 0; j < 4; j++) acc[i][j] = {0.f, 0.f, 0.f, 0.f};

    size_t aoff = (size_t)(m0 + wv * 32 + (lane >> 2)) * K + (lane & 3) * 8 + kz;
    size_t boff = (size_t)(n0 + wv * 32 + (lane >> 2)) * K + (lane & 3) * 8 + kz;
    const ushort_t* gAh = Ah + aoff;
    const ushort_t* gAl = Al_ + aoff;
    const ushort_t* gBh = Bh + boff;
    const ushort_t* gBl = Bl_ + boff;

    for (int k0 = 0; k0 < Kc; k0 += 32) {
        gld16(gAh, &sAh[(wv * 32) * 32]);
        gld16(gAh + (size_t)16 * K, &sAh[(wv * 32 + 16) * 32]);
        gld16(gAl, &sAl[(wv * 32) * 32]);
        gld16(gAl + (size_t)16 * K, &sAl[(wv * 32 + 16) * 32]);
        gld16(gBh, &sBh[(wv * 32) * 32]);
        gld16(gBh + (size_t)16 * K, &sBh[(wv * 32 + 16) * 32]);
        gld16(gBl, &sBl[(wv * 32) * 32]);
        gld16(gBl + (size_t)16 * K, &sBl[(wv * 32 + 16) * 32]);
        gAh += 32; gAl += 32; gBh += 32; gBl += 32;
        __syncthreads();
        half8 ah[4], al[4], bh[4], bl[4];
#pragma unroll
        for (int i = 0; i < 4; i++) {
            int off = (wm + i * 16 + fr) * 32 + fq * 8;
            ah[i] = *(const half8*)&sAh[off];
            al[i] = *(const half8*)&sAl[off];
        }
#pragma unroll
        for (int j = 0; j < 4; j++) {
            int off = (wn + j * 16 + fr) * 32 + fq * 8;
            bh[j] = *(const half8*)&sBh[off];
            bl[j] = *(const half8*)&sBl[off];
        }
#pragma unroll
        for (int i = 0; i < 4; i++)
#pragma unroll
            for (int j = 0; j < 4; j++) {
                acc[i][j] = __builtin_amdgcn_mfma_f32_16x16x32_f16(ah[i], bh[j], acc[i][j], 0, 0, 0);
                acc[i][j] = __builtin_amdgcn_mfma_f32_16x16x32_f16(ah[i], bl[j], acc[i][j], 0, 0, 0);
                acc[i][j] = __builtin_amdgcn_mfma_f32_16x16x32_f16(al[i], bh[j], acc[i][j], 0, 0, 0);
            }
        __syncthreads();
    }
    float* Cw = C + (size_t)blockIdx.z * (size_t)zpart * (size_t)ldc;
#pragma unroll
    for (int i = 0; i < 4; i++)
#pragma unroll
        for (int j = 0; j < 4; j++)
#pragma unroll
            for (int r = 0; r < 4; r++) {
                int row = m0 + wm + i * 16 + fq * 4 + r;
                int col = n0 + wn + j * 16 + fr;
                if (zpart)
                    Cw[(size_t)row * ldc + col] = acc[i][j][r];
                else
                    atomicAdd(&C[(size_t)row * ldc + col], acc[i][j][r]);
            }
}

// ---------------- grouped f16 MFMA GEMM (MoE): gathered A rows, scattered C rows ----------------
__global__ __launch_bounds__(256) void moe_gemm(const ushort_t* __restrict__ Ab,
                                                const ushort_t* __restrict__ BtAll,
                                                const int* __restrict__ cnt,
                                                const int* __restrict__ ridx_g,
                                                const int* __restrict__ oidx_g,
                                                ushort_t* __restrict__ Cout,
                                                int N, int K, int ebase) {
    int e = ebase + blockIdx.z;
    int nt = cnt[e];
    int mt0 = blockIdx.y * 128;
    if (mt0 >= nt) return;
    const ushort_t* Bt = BtAll + (size_t)blockIdx.z * N * K;
    int n0 = blockIdx.x * 128;
    __shared__ ushort_t Al[4096];
    __shared__ ushort_t Bl[4096];
    __shared__ int ridx[128], oidx[128];
    int tid = threadIdx.x, lane = tid & 63, wv = tid >> 6;
    if (tid < 128) {
        int ii = mt0 + tid;
        bool v = ii < nt;
        ridx[tid] = v ? ridx_g[e * T_TOK + ii] : -1;
        oidx[tid] = v ? oidx_g[e * T_TOK + ii] : -1;
    }
    __syncthreads();
    int wm = (wv & 1) * 64, wn = (wv >> 1) * 64;
    int fr = lane & 15, fq = lane >> 4;
    f32x4 acc[4][4];
#pragma unroll
    for (int i = 0; i < 4; i++)
#pragma unroll
        for (int j = 0; j < 4; j++) acc[i][j] = {0.f, 0.f, 0.f, 0.f};

    int arow = tid >> 1, akoff = (tid & 1) * 16;
    int ra = ridx[arow];
    const ushort_t* asrc = (ra >= 0) ? (Ab + (size_t)ra * K + akoff) : (const ushort_t*)0;
    const ushort_t* gB = Bt + (size_t)(n0 + wv * 32 + (lane >> 2)) * K + (lane & 3) * 8;

    for (int k0 = 0; k0 < K; k0 += 32) {
        uint4 v0 = {0, 0, 0, 0}, v1 = {0, 0, 0, 0};
        if (ra >= 0) {
            v0 = *(const uint4*)(asrc);
            v1 = *(const uint4*)(asrc + 8);
            asrc += 32;
        }
        gld16(gB, &Bl[(wv * 32) * 32]);
        gld16(gB + (size_t)16 * K, &Bl[(wv * 32 + 16) * 32]);
        gB += 32;
        *(uint4*)&Al[arow * 32 + akoff] = v0;
        *(uint4*)&Al[arow * 32 + akoff + 8] = v1;
        __syncthreads();
        half8 af[4], bfr[4];
#pragma unroll
        for (int i = 0; i < 4; i++) af[i] = *(const half8*)&Al[(wm + i * 16 + fr) * 32 + fq * 8];
#pragma unroll
        for (int j = 0; j < 4; j++) bfr[j] = *(const half8*)&Bl[(wn + j * 16 + fr) * 32 + fq * 8];
#pragma unroll
        for (int i = 0; i < 4; i++)
#pragma unroll
            for (int j = 0; j < 4; j++)
                acc[i][j] = __builtin_amdgcn_mfma_f32_16x16x32_f16(af[i], bfr[j], acc[i][j], 0, 0, 0);
        __syncthreads();
    }
#pragma unroll
    for (int i = 0; i < 4; i++)
#pragma unroll
        for (int j = 0; j < 4; j++)
#pragma unroll
            for (int r = 0; r < 4; r++) {
                int lr = wm + i * 16 + fq * 4 + r;
                if (mt0 + lr < nt) {
                    int orow = oidx[lr];
                    Cout[(size_t)orow * N + n0 + wn + j * 16 + fr] = f2h(acc[i][j][r]);
                }
            }
}

// ------- QK RMSNorm + neox RoPE; writes Q and K directly as f16 hi/lo planes -------
// Q planes: [t][NH*128]; K planes: [t][NKV*128]
__global__ __launch_bounds__(128) void qk_rope_prep(const float* __restrict__ qkv,
                                                    const float* __restrict__ qw,
                                                    const float* __restrict__ kw,
                                                    const int* __restrict__ positions,
                                                    ushort_t* __restrict__ Qhp,
                                                    ushort_t* __restrict__ Qlp,
                                                    ushort_t* __restrict__ Khp,
                                                    ushort_t* __restrict__ Klp) {
    int t = blockIdx.x / (NH + NKV);
    int hh = blockIdx.x % (NH + NKV);
    bool isq = hh < NH;
    const float* x = isq ? qkv + (size_t)t * 3072 + hh * HD
                         : qkv + (size_t)t * 3072 + 2048 + (hh - NH) * HD;
    const float* w = isq ? qw : kw;
    int tid = threadIdx.x;
    float v = x[tid];
    float ss = v * v;
#pragma unroll
    for (int o = 32; o; o >>= 1) ss += __shfl_down(ss, o);
    __shared__ float red[2];
    if ((tid & 63) == 0) red[tid >> 6] = ss;
    __syncthreads();
    float tot = red[0] + red[1];
    float scale = rsqrtf(tot / (float)HD + EPSF);
    float xn = v * scale * w[tid];
    __shared__ float buf[HD];
    buf[tid] = xn;
    __syncthreads();
    if (tid < 64) {
        float x1 = buf[tid], x2 = buf[tid + 64];
        float invf = expf(-((float)tid / 64.0f) * logf(1000000.0f));
        float ang = (float)positions[t] * invf;
        float c = cosf(ang), s = sinf(ang);
        float xa = x1 * c - x2 * s;
        float xb = x2 * c + x1 * s;
        size_t base = isq ? ((size_t)t * (NH * HD) + hh * HD)
                          : ((size_t)t * (NKV * HD) + (hh - NH) * HD);
        ushort_t* oh = isq ? Qhp : Khp;
        ushort_t* ol = isq ? Qlp : Klp;
        ushort_t ha = f2h(xa);
        oh[base + tid] = ha;
        ol[base + tid] = f2h(xa - h2f_(ha));
        ushort_t hb = f2h(xb);
        oh[base + tid + 64] = hb;
        ol[base + tid + 64] = f2h(xb - h2f_(hb));
    }
}

// ---------------- MFMA flash attention: f16 hi/lo planes, NAMED-register prefetch, KSPLIT=2 ----------------
// grid (qtile, head, z); block z handles k-tiles [kt0, kt1) with own (m,l);
// writes normalized partial O (f32) + per-row (m,l); attn_combine merges.
#define ATT_SCALE 0.08838834764831845f
__global__ __launch_bounds__(256) void attn_mfma(const ushort_t* __restrict__ Qhp,
                                                 const ushort_t* __restrict__ Qlp,
                                                 const ushort_t* __restrict__ Khp,
                                                 const ushort_t* __restrict__ Klp,
                                                 const ushort_t* __restrict__ Vthp,
                                                 const ushort_t* __restrict__ Vtlp,
                                                 float* __restrict__ Op0,
                                                 float* __restrict__ Op1,
                                                 float* __restrict__ mlb) {
    __shared__ _Float16 sKh[64 * 136], sKl[64 * 136];   // K rows, padded stride 136
    __shared__ _Float16 sVh[128 * 72], sVl[128 * 72];   // Vt rows [d][krow], padded stride 72
    __shared__ _Float16 sPh[64 * 72], sPl[64 * 72];     // P [qrow][krow]

    int qi = blockIdx.x, h = blockIdx.y, z = blockIdx.z;
    int q0 = qi * 64, g = h >> 2;
    int tid = threadIdx.x, lane = tid & 63, wv = tid >> 6;
    int quad = lane >> 4, n16 = lane & 15;
    int nt = qi + 1;
    int halfn = (nt + 1) >> 1;
    int kt0 = z ? halfn : 0;
    int kt1 = z ? nt : halfn;

    // ---- Q A-frags direct from global planes (once per block) ----
    half8 qh[4], ql[4];
#pragma unroll
    for (int ks = 0; ks < 4; ks++) {
        size_t off = (size_t)(q0 + wv * 16 + n16) * (NH * HD) + h * HD + ks * 32 + quad * 8;
        qh[ks] = *(const half8*)&Qhp[off];
        ql[ks] = *(const half8*)&Qlp[off];
    }

    // NAMED staging registers (no arrays -> guaranteed VGPRs, rule #20)
    uint4 kh0, kh1, kh2, kh3, kl0, kl1, kl2, kl3;
    uint4 vh0, vh1, vh2, vh3, vl0, vl1, vl2, vl3;

#define STAGE_LOAD(K0)                                                                \
    {                                                                                 \
        size_t bk = (size_t)((K0) + (tid >> 4)) * 512 + g * 128 + (tid & 15) * 8;     \
        kh0 = *(const uint4*)&Khp[bk];                                                \
        kh1 = *(const uint4*)&Khp[bk + 16 * 512];                                     \
        kh2 = *(const uint4*)&Khp[bk + 32 * 512];                                     \
        kh3 = *(const uint4*)&Khp[bk + 48 * 512];                                     \
        kl0 = *(const uint4*)&Klp[bk];                                                \
        kl1 = *(const uint4*)&Klp[bk + 16 * 512];                                     \
        kl2 = *(const uint4*)&Klp[bk + 32 * 512];                                     \
        kl3 = *(const uint4*)&Klp[bk + 48 * 512];                                     \
        size_t bv = (size_t)(g * 128 + (tid >> 3)) * 1024 + (K0) + (tid & 7) * 8;     \
        vh0 = *(const uint4*)&Vthp[bv];                                               \
        vh1 = *(const uint4*)&Vthp[bv + 32 * 1024];                                   \
        vh2 = *(const uint4*)&Vthp[bv + 64 * 1024];                                   \
        vh3 = *(const uint4*)&Vthp[bv + 96 * 1024];                                   \
        vl0 = *(const uint4*)&Vtlp[bv];                                               \
        vl1 = *(const uint4*)&Vtlp[bv + 32 * 1024];                                   \
        vl2 = *(const uint4*)&Vtlp[bv + 64 * 1024];                                   \
        vl3 = *(const uint4*)&Vtlp[bv + 96 * 1024];                                   \
    }

#define STAGE_WRITE()                                                                 \
    {                                                                                 \
        int wk = (tid >> 4) * 136 + (tid & 15) * 8;                                   \
        *(uint4*)&sKh[wk] = kh0;                                                      \
        *(uint4*)&sKh[wk + 16 * 136] = kh1;                                           \
        *(uint4*)&sKh[wk + 32 * 136] = kh2;                                           \
        *(uint4*)&sKh[wk + 48 * 136] = kh3;                                           \
        *(uint4*)&sKl[wk] = kl0;                                                      \
        *(uint4*)&sKl[wk + 16 * 136] = kl1;                                           \
        *(uint4*)&sKl[wk + 32 * 136] = kl2;                                           \
        *(uint4*)&sKl[wk + 48 * 136] = kl3;                                           \
        int wva = (tid >> 3) * 72 + (tid & 7) * 8;                                    \
        *(uint4*)&sVh[wva] = vh0;                                                     \
        *(uint4*)&sVh[wva + 32 * 72] = vh1;                                           \
        *(uint4*)&sVh[wva + 64 * 72] = vh2;                                           \
        *(uint4*)&sVh[wva + 96 * 72] = vh3;                                           \
        *(uint4*)&sVl[wva] = vl0;                                                     \
        *(uint4*)&sVl[wva + 32 * 72] = vl1;                                           \
        *(uint4*)&sVl[wva + 64 * 72] = vl2;                                           \
        *(uint4*)&sVl[wva + 96 * 72] = vl3;                                           \
    }

    float m_r[4], l_r[4];
#pragma unroll
    for (int r = 0; r < 4; r++) { m_r[r] = -1e30f; l_r[r] = 0.f; }
    f32x4 acc[8];
#pragma unroll
    for (int d = 0; d < 8; d++) acc[d] = {0.f, 0.f, 0.f, 0.f};

    if (kt0 < kt1) {
        // prologue: stage first tile
        STAGE_LOAD(kt0 * 64);
        STAGE_WRITE();
        __syncthreads();

        for (int kt = kt0; kt < kt1; kt++) {
            // issue next tile's global loads early (hidden under compute)
            if (kt + 1 < kt1) STAGE_LOAD((kt + 1) * 64);

            // ---- S = Q K^T : per wave 16q x 64k, hi*hi + hi*lo + lo*hi ----
            f32x4 s[4];
#pragma unroll
            for (int jt = 0; jt < 4; jt++) s[jt] = {0.f, 0.f, 0.f, 0.f};
#pragma unroll
            for (int ks = 0; ks < 4; ks++)
#pragma unroll
                for (int jt = 0; jt < 4; jt++) {
                    int off = (jt * 16 + n16) * 136 + ks * 32 + quad * 8;
                    half8 bh = *(const half8*)&sKh[off];
                    half8 bl = *(const half8*)&sKl[off];
                    s[jt] = __builtin_amdgcn_mfma_f32_16x16x32_f16(qh[ks], bh, s[jt], 0, 0, 0);
                    s[jt] = __builtin_amdgcn_mfma_f32_16x16x32_f16(qh[ks], bl, s[jt], 0, 0, 0);
                    s[jt] = __builtin_amdgcn_mfma_f32_16x16x32_f16(ql[ks], bh, s[jt], 0, 0, 0);
                }

            // ---- online softmax in C-layout (row = quad*4+r, col = jt*16+n16) ----
            bool last = (kt == qi);
            int lrow_base = wv * 16 + quad * 4;
#pragma unroll
            for (int r = 0; r < 4; r++) {
                float rm = -1e30f;
#pragma unroll
                for (int jt = 0; jt < 4; jt++) {
                    float sv = s[jt][r] * ATT_SCALE;
                    if (last && (jt * 16 + n16 > lrow_base + r)) sv = -1e30f;
                    s[jt][r] = sv;
                    rm = fmaxf(rm, sv);
                }
                rm = fmaxf(rm, __shfl_xor(rm, 1));
                rm = fmaxf(rm, __shfl_xor(rm, 2));
                rm = fmaxf(rm, __shfl_xor(rm, 4));
                rm = fmaxf(rm, __shfl_xor(rm, 8));
                float mo = m_r[r], mn = fmaxf(mo, rm);
                float al = __expf(mo - mn);
                float ls = 0.f;
#pragma unroll
                for (int jt = 0; jt < 4; jt++) {
                    float p = __expf(s[jt][r] - mn);
                    ls += p;
                    _Float16 phi = (_Float16)p;
                    int poff = (lrow_base + r) * 72 + jt * 16 + n16;
                    sPh[poff] = phi;
                    sPl[poff] = (_Float16)(p - (float)phi);
                }
                ls += __shfl_xor(ls, 1);
                ls += __shfl_xor(ls, 2);
                ls += __shfl_xor(ls, 4);
                ls += __shfl_xor(ls, 8);
                l_r[r] = l_r[r] * al + ls;
                m_r[r] = mn;
#pragma unroll
                for (int dt = 0; dt < 8; dt++) acc[dt][r] *= al;
            }
            __syncthreads();  // P visible; K fully consumed

            // ---- PV: P (A via LDS round-trip) x V (B from transposed Vt) ----
            half8 pah[2], pal[2];
#pragma unroll
            for (int ks = 0; ks < 2; ks++) {
                int off = (wv * 16 + n16) * 72 + ks * 32 + quad * 8;
                pah[ks] = *(const half8*)&sPh[off];
                pal[ks] = *(const half8*)&sPl[off];
            }
#pragma unroll
            for (int dt = 0; dt < 8; dt++)
#pragma unroll
                for (int ks = 0; ks < 2; ks++) {
                    int off = (dt * 16 + n16) * 72 + ks * 32 + quad * 8;
                    half8 vh = *(const half8*)&sVh[off];
                    half8 vl = *(const half8*)&sVl[off];
                    acc[dt] = __builtin_amdgcn_mfma_f32_16x16x32_f16(pah[ks], vh, acc[dt], 0, 0, 0);
                    acc[dt] = __builtin_amdgcn_mfma_f32_16x16x32_f16(pah[ks], vl, acc[dt], 0, 0, 0);
                    acc[dt] = __builtin_amdgcn_mfma_f32_16x16x32_f16(pal[ks], vh, acc[dt], 0, 0, 0);
                }
            __syncthreads();  // V and P consumed

            if (kt + 1 < kt1) {
                STAGE_WRITE();   // vmcnt wait on prefetched regs lands here
                __syncthreads();
            }
        }
    }

    // ---- epilogue: normalized partial O (f32) + per-row (m, l) ----
    float* Op = z ? Op1 : Op0;
#pragma unroll
    for (int r = 0; r < 4; r++) {
        float inv = (l_r[r] > 0.f) ? 1.f / l_r[r] : 0.f;
        int row = q0 + wv * 16 + quad * 4 + r;
#pragma unroll
        for (int dt = 0; dt < 8; dt++)
            Op[(size_t)row * 2048 + h * HD + dt * 16 + n16] = acc[dt][r] * inv;
        if (n16 == 0) {
            size_t mi = ((size_t)(z * T_TOK + row) * NH + h) * 2;
            mlb[mi] = m_r[r];
            mlb[mi + 1] = l_r[r];
        }
    }
#undef STAGE_LOAD
#undef STAGE_WRITE
}

// ---------------- merge the two k-split partials -> o f16 hi/lo planes ----------------
__global__ __launch_bounds__(256) void attn_combine(const float* __restrict__ Op0,
                                                    const float* __restrict__ Op1,
                                                    const float* __restrict__ mlb,
                                                    ushort_t* __restrict__ ohp,
                                                    ushort_t* __restrict__ olp) {
    int idx = blockIdx.x * 256 + threadIdx.x;
    int t = idx >> 11;
    int h = (idx >> 7) & 15;
    size_t mi0 = ((size_t)t * NH + h) * 2;
    size_t mi1 = ((size_t)(T_TOK + t) * NH + h) * 2;
    float m0 = mlb[mi0], l0 = mlb[mi0 + 1];
    float m1 = mlb[mi1], l1 = mlb[mi1 + 1];
    float M = fmaxf(m0, m1);
    float w0 = l0 * __expf(m0 - M);
    float w1 = l1 * __expf(m1 - M);
    float val = (w0 * Op0[idx] + w1 * Op1[idx]) / (w0 + w1);
    _Float16 hi = (_Float16)val;
    ohp[idx] = __builtin_bit_cast(ushort_t, hi);
    olp[idx] = f2h(val - (float)hi);
}

// ---------------- router: softmax over 8 experts, top-2, bucket by expert ----------------
__global__ __launch_bounds__(256) void router(const float* __restrict__ h2,
                                              const float* __restrict__ gate_w,
                                              int* __restrict__ cnt,
                                              int* __restrict__ btok,
                                              int* __restrict__ bslot,
                                              float* __restrict__ wslot) {
    int t = blockIdx.x, tid = threadIdx.x;
    int e = tid & 7, c = tid >> 3;
    float part = 0.f;
    for (int i = 0; i < 64; i++) {
        int hh = c * 64 + i;
        part += h2[(size_t)t * H_DIM + hh] * gate_w[hh * NEXP + e];
    }
    __shared__ float red[256];
    red[tid] = part;
    __syncthreads();
    for (int s = 128; s >= 8; s >>= 1) {
        if (tid < s) red[tid] += red[tid + s];
        __syncthreads();
    }
    if (tid == 0) {
        float mx = -1e30f;
        for (int i = 0; i < NEXP; i++) mx = fmaxf(mx, red[i]);
        float p[NEXP];
        for (int i = 0; i < NEXP; i++) p[i] = expf(red[i] - mx);
        int i1 = 0;
        for (int i = 1; i < NEXP; i++) if (p[i] > p[i1]) i1 = i;
        int i2 = (i1 == 0) ? 1 : 0;
        for (int i = 0; i < NEXP; i++) if (i != i1 && p[i] > p[i2]) i2 = i;
        float denom = p[i1] + p[i2];
        wslot[2 * t] = p[i1] / denom;
        wslot[2 * t + 1] = p[i2] / denom;
        int pos = atomicAdd(&cnt[i1], 1);
        btok[i1 * T_TOK + pos] = t; bslot[i1 * T_TOK + pos] = 2 * t;
        pos = atomicAdd(&cnt[i2], 1);
        btok[i2 * T_TOK + pos] = t; bslot[i2 * T_TOK + pos] = 2 * t + 1;
    }
}

// ---------------- SwiGLU: gu f16 [2048][1536] -> act f16 [2048][768] ----------------
__global__ __launch_bounds__(256) void swiglu(const ushort_t* __restrict__ gu,
                                              ushort_t* __restrict__ act) {
    int idx = blockIdx.x * 256 + threadIdx.x;
    int s = idx / I_DIM, i = idx - s * I_DIM;
    float g = h2f_(gu[(size_t)s * (2 * I_DIM) + i]);
    float u = h2f_(gu[(size_t)s * (2 * I_DIM) + I_DIM + i]);
    act[idx] = f2h(g / (1.f + expf(-g)) * u);
}

// ---------------- combine: out[t] = w0*dbuf[2t] + w1*dbuf[2t+1] ----------------
__global__ __launch_bounds__(256) void combine(const ushort_t* __restrict__ dbuf,
                                               const float* __restrict__ wslot,
                                               float* __restrict__ out) {
    int idx = blockIdx.x * 256 + threadIdx.x;
    int t = idx >> 11;
    out[idx] = wslot[2 * t] * h2f_(dbuf[(size_t)(2 * t) * H_DIM + (idx & 2047)]) +
               wslot[2 * t + 1] * h2f_(dbuf[(size_t)(2 * t + 1) * H_DIM + (idx & 2047)]);
}

extern "C" void kernel_launch(void* const* d_in, const int* in_sizes, int n_in,
                              void* d_out, int out_size, void* d_ws, size_t ws_size,
                              hipStream_t stream) {
    const int* positions = (const int*)d_in[0];
    const float* hs = (const float*)d_in[1];
    const float* resid = (const float*)d_in[2];
    const float* w_qkv = (const float*)d_in[3];
    const float* w_o = (const float*)d_in[4];
    const float* q_norm_w = (const float*)d_in[5];
    const float* k_norm_w = (const float*)d_in[6];
    const float* ln1_w = (const float*)d_in[7];
    const float* ln2_w = (const float*)d_in[8];
    const float* gate_w = (const float*)d_in[9];
    const float* w_gu = (const float*)d_in[10];
    const float* w_dn = (const float*)d_in[11];

    float* out = (float*)d_out;
    float* res2 = out + (size_t)T_TOK * H_DIM;

    const size_t MB = 1ull << 20;
    char* W = (char*)d_ws;
    // ---- per-step disjointness-audited layout ----
    // 0-8:   res1 (live 2-8) | gub 0-6 (live 10-11) | dbuf 0-8 (live 12-13)
    float*    res1   = (float*)(W + 0);
    ushort_t* gub    = (ushort_t*)(W + 0);
    ushort_t* dbuf   = (ushort_t*)(W + 0);
    // 8-16:  h1h 8-12 / h1l 12-16 (live 2-3) | ohp 8-12 / olp 12-16 (live 5.5-7)
    //        | h2h 8-12 (live 8-10) | actb 12-15 (live 11-12)
    ushort_t* h1h    = (ushort_t*)(W + 8 * MB);
    ushort_t* h1l    = (ushort_t*)(W + 12 * MB);
    ushort_t* ohp    = (ushort_t*)(W + 8 * MB);
    ushort_t* olp    = (ushort_t*)(W + 12 * MB);
    ushort_t* h2h    = (ushort_t*)(W + 8 * MB);
    ushort_t* actb   = (ushort_t*)(W + 12 * MB);
    // 16-28: qkvf (live 3-4) | Op0 16-24 + ml 24-24.25 (live 5-5.5)
    //        | wTh_o 16-24 / wTl_o 24-32 (live 6-7) | h2f 16-24 (live 8-9) | wTmoe 16-41.2 (live 10-12)
    float*    qkvf   = (float*)(W + 16 * MB);
    float*    attnO0 = (float*)(W + 16 * MB);
    float*    attnml = (float*)(W + 24 * MB);
    ushort_t* wTh_o  = (ushort_t*)(W + 16 * MB);
    ushort_t* wTl_o  = (ushort_t*)(W + 24 * MB);
    float*    h2f    = (float*)(W + 16 * MB);
    ushort_t* wTmoe  = (ushort_t*)(W + 16 * MB);
    // 28-40: qkv weight transposes 28-34/34-40 (live step 3) | attn planes 28-40 (live 4-5)
    ushort_t* wTh_q  = (ushort_t*)(W + 28 * MB);
    ushort_t* wTl_q  = (ushort_t*)(W + 34 * MB);
    ushort_t* Qhp    = (ushort_t*)(W + 28 * MB);  // 4 MiB
    ushort_t* Qlp    = (ushort_t*)(W + 32 * MB);  // 4 MiB
    ushort_t* Khp    = (ushort_t*)(W + 36 * MB);  // 1 MiB
    ushort_t* Klp    = (ushort_t*)(W + 37 * MB);  // 1 MiB
    ushort_t* Vthp   = (ushort_t*)(W + 38 * MB);  // 1 MiB
    ushort_t* Vtlp   = (ushort_t*)(W + 39 * MB);  // 1 MiB
    // 40-48: Op1 (live 5-5.5) | oprojf 32-48 (live 7-8; Op1 dead by then)
    float*    attnO1 = (float*)(W + 40 * MB);
    float*    oprojf = (float*)(W + 32 * MB);
    // 48+:   buckets (live 9-13)
    int*      cnt    = (int*)(W + 48 * MB);
    int*      btok   = cnt + 16;
    int*      bslot  = btok + NEXP * T_TOK;
    float*    wslot  = (float*)(bslot + NEXP * T_TOK);

    // 1+2. res1 = hs + resid; h1 = rms(res1)*ln1 as f16 hi/lo
    add_rms1<<<T_TOK, 256, 0, stream>>>(hs, resid, ln1_w, res1, h1h, h1l);
    // 3. qkv = h1 @ w_qkv in two N-chunks of 1536, split-K=4 (atomic f32)
    hipMemsetAsync(qkvf, 0, (size_t)T_TOK * 3072 * 4, stream);
    for (int c = 0; c < 2; c++) {
        castT_hl<<<dim3(1536 / 32, 2048 / 32), 256, 0, stream>>>(
            w_qkv + c * 1536, wTh_q, wTl_q, 2048, 3072);
        gemm_f16x3<<<dim3(1536 / 128, 1024 / 128, 4), 256, 0, stream>>>(
            h1h, h1l, wTh_q, wTl_q, qkvf + c * 1536, 3072, 2048, 0);
    }
    // 4. q/k RMSNorm + RoPE -> Q/K f16 hi/lo planes; V transpose -> Vt planes
    qk_rope_prep<<<T_TOK * (NH + NKV), 128, 0, stream>>>(qkvf, q_norm_w, k_norm_w, positions,
                                                         Qhp, Qlp, Khp, Klp);
    prep_vt<<<dim3(HD / 32, T_TOK / 32, NKV), 256, 0, stream>>>(qkvf, Vthp, Vtlp);
    // 5. MFMA flash attention, k-split=2 -> partial O (16-24, 40-48) + ml (24MB)
    attn_mfma<<<dim3(T_TOK / 64, NH, 2), 256, 0, stream>>>(Qhp, Qlp, Khp, Klp, Vthp, Vtlp,
                                                           attnO0, attnO1, attnml);
    // 5.5. merge partials -> ohp/olp f16 planes at 8-16
    attn_combine<<<(T_TOK * H_DIM) / 256, 256, 0, stream>>>(attnO0, attnO1, attnml, ohp, olp);
    // 6. w_o transpose hi/lo -> 16-32 (attn partials dead)
    castT_hl<<<dim3(2048 / 32, 2048 / 32), 256, 0, stream>>>(w_o, wTh_o, wTl_o, 2048, 2048);
    // 7. oproj = attn_out @ w_o, split-K=2 partial mode -> 32-48
    gemm_f16x3<<<dim3(2048 / 128, 1024 / 128, 2), 256, 0, stream>>>(
        ohp, olp, wTh_o, wTl_o, oprojf, 2048, 2048, 1024);
    // 8. res2 = oproj0 + oproj1 + res1 (-> d_out); h2 f32 (16-24) + f16 (8-12)
    add_rms2<<<T_TOK, 256, 0, stream>>>(oprojf, oprojf + (size_t)1024 * 2048, res1, ln2_w,
                                        res2, h2f, h2h);
    // 9. router (f32 logits)
    hipMemsetAsync(cnt, 0, NEXP * sizeof(int), stream);
    router<<<T_TOK, 256, 0, stream>>>(h2f, gate_w, cnt, btok, bslot, wslot);
    // 10. MoE gate_up in 2 chunks of 4 experts (weights at 16+; gub at 0)
    for (int c = 0; c < 2; c++) {
        castT_h<<<dim3(1536 / 32, 2048 / 32, 4), 256, 0, stream>>>(
            w_gu + (size_t)c * 4 * 2048 * 1536, wTmoe, 2048, 1536, (size_t)2048 * 1536);
        moe_gemm<<<dim3(1536 / 128, 8, 4), 256, 0, stream>>>(
            h2h, wTmoe, cnt, btok, bslot, gub, 1536, 2048, c * 4);
    }
    // 11. SwiGLU: gub (0-6) -> actb (12-15)
    swiglu<<<(2048 * I_DIM) / 256, 256, 0, stream>>>(gub, actb);
    // 12. MoE down, all 8 experts (weights 16-40; actb 12-15; dbuf 0-8)
    castT_h<<<dim3(2048 / 32, 768 / 32, 8), 256, 0, stream>>>(
        w_dn, wTmoe, 768, 2048, (size_t)768 * 2048);
    moe_gemm<<<dim3(2048 / 128, 8, 8), 256, 0, stream>>>(
        actb, wTmoe, cnt, bslot, bslot, dbuf, 2048, 768, 0);
    // 13. weighted combine
    combine<<<(T_TOK * H_DIM) / 256, 256, 0, stream>>>(dbuf, wslot, out);
}

// Round 7
// 603.385 us; speedup vs baseline: 1.1687x; 1.1284x over previous
//
#include <hip/hip_runtime.h>
#include <hip/hip_bf16.h>

#define T_TOK 1024
#define H_DIM 2048
#define NH 16
#define NKV 4
#define HD 128
#define NEXP 8
#define I_DIM 768
#define EPSF 1e-6f

typedef unsigned short ushort_t;
typedef __attribute__((ext_vector_type(8))) _Float16 half8;
typedef __attribute__((ext_vector_type(4))) float f32x4;

__device__ __forceinline__ ushort_t f2h(float x) {
    _Float16 h = (_Float16)x;
    return __builtin_bit_cast(ushort_t, h);
}
__device__ __forceinline__ float h2f_(ushort_t u) {
    return (float)__builtin_bit_cast(_Float16, u);
}
__device__ __forceinline__ void gld16(const ushort_t* g, ushort_t* l) {
    __builtin_amdgcn_global_load_lds(
        (const __attribute__((address_space(1))) unsigned int*)g,
        (__attribute__((address_space(3))) unsigned int*)l, 16, 0, 0);
}

// ---------------- residual add + RMSNorm -> res f32, h f16 ----------------
__global__ __launch_bounds__(256) void add_rms1(const float* __restrict__ a,
                                                const float* __restrict__ b,
                                                const float* __restrict__ w,
                                                float* __restrict__ res,
                                                ushort_t* __restrict__ hh) {
    int t = blockIdx.x, tid = threadIdx.x;
    float v[8];
    float ss = 0.f;
#pragma unroll
    for (int i = 0; i < 8; i++) {
        int idx = t * H_DIM + tid + i * 256;
        v[i] = a[idx] + b[idx];
        res[idx] = v[i];
        ss += v[i] * v[i];
    }
#pragma unroll
    for (int o = 32; o; o >>= 1) ss += __shfl_down(ss, o);
    __shared__ float red[4];
    if ((tid & 63) == 0) red[tid >> 6] = ss;
    __syncthreads();
    float tot = red[0] + red[1] + red[2] + red[3];
    float scale = rsqrtf(tot / (float)H_DIM + EPSF);
#pragma unroll
    for (int i = 0; i < 8; i++) {
        int c = tid + i * 256;
        hh[t * H_DIM + c] = f2h(v[i] * scale * w[c]);
    }
}

// ------- residual add + RMSNorm, 2 partial inputs (split-K oproj) -> res f32, h f32, h f16 -------
__global__ __launch_bounds__(256) void add_rms2(const float* __restrict__ a0,
                                                const float* __restrict__ a1,
                                                const float* __restrict__ b,
                                                const float* __restrict__ w,
                                                float* __restrict__ res,
                                                float* __restrict__ hf,
                                                ushort_t* __restrict__ hh) {
    int t = blockIdx.x, tid = threadIdx.x;
    float v[8];
    float ss = 0.f;
#pragma unroll
    for (int i = 0; i < 8; i++) {
        int idx = t * H_DIM + tid + i * 256;
        v[i] = a0[idx] + a1[idx] + b[idx];
        res[idx] = v[i];
        ss += v[i] * v[i];
    }
#pragma unroll
    for (int o = 32; o; o >>= 1) ss += __shfl_down(ss, o);
    __shared__ float red[4];
    if ((tid & 63) == 0) red[tid >> 6] = ss;
    __syncthreads();
    float tot = red[0] + red[1] + red[2] + red[3];
    float scale = rsqrtf(tot / (float)H_DIM + EPSF);
#pragma unroll
    for (int i = 0; i < 8; i++) {
        int c = tid + i * 256;
        float hv = v[i] * scale * w[c];
        hf[t * H_DIM + c] = hv;
        hh[t * H_DIM + c] = f2h(hv);
    }
}

// ---------------- cast+transpose f32 [R][C(ld)] -> f16 [C][R], z-batched ----------------
__global__ __launch_bounds__(256) void castT_h(const float* __restrict__ in,
                                               ushort_t* __restrict__ out,
                                               int R, int ld, size_t zstride) {
    in += (size_t)blockIdx.z * zstride;
    out += (size_t)blockIdx.z * zstride;
    __shared__ float tile[32][33];
    int r0 = blockIdx.y * 32, c0 = blockIdx.x * 32;
    int tx = threadIdx.x & 31, ty = threadIdx.x >> 5;
#pragma unroll
    for (int i = 0; i < 4; i++)
        tile[ty + 8 * i][tx] = in[(size_t)(r0 + ty + 8 * i) * ld + c0 + tx];
    __syncthreads();
#pragma unroll
    for (int i = 0; i < 4; i++)
        out[(size_t)(c0 + ty + 8 * i) * R + r0 + tx] = f2h(tile[tx][ty + 8 * i]);
}

// ---------------- V transpose+cast: qkv f32 V region -> Vt f16 [g][128][1024] ----------------
__global__ __launch_bounds__(256) void prep_vt(const float* __restrict__ qkv,
                                               ushort_t* __restrict__ vh) {
    __shared__ float tile[32][33];
    int g = blockIdx.z;
    int t0 = blockIdx.y * 32, d0 = blockIdx.x * 32;
    int tx = threadIdx.x & 31, ty = threadIdx.x >> 5;
#pragma unroll
    for (int i = 0; i < 4; i++)
        tile[ty + 8 * i][tx] = qkv[(size_t)(t0 + ty + 8 * i) * 3072 + 2560 + g * HD + d0 + tx];
    __syncthreads();
#pragma unroll
    for (int i = 0; i < 4; i++)
        vh[(size_t)(g * HD + d0 + ty + 8 * i) * T_TOK + t0 + tx] = f2h(tile[tx][ty + 8 * i]);
}

// ------- f16 MFMA GEMM, split-K: zpart==0 -> atomic accumulate into zeroed C;
//         zpart>0 -> each z writes its own partial at C + z*zpart*ldc -------
__global__ __launch_bounds__(256) void gemm_f16(const ushort_t* __restrict__ Ah,
                                                const ushort_t* __restrict__ Bh,
                                                float* __restrict__ C,
                                                int ldc, int K, int zpart) {
    __shared__ ushort_t sA[4096], sB[4096];
    int tid = threadIdx.x, lane = tid & 63, wv = tid >> 6;
    int m0 = blockIdx.y * 128, n0 = blockIdx.x * 128;
    int Kc = K / gridDim.z;
    int kz = blockIdx.z * Kc;
    int wm = (wv & 1) * 64, wn = (wv >> 1) * 64;
    int fr = lane & 15, fq = lane >> 4;
    f32x4 acc[4][4];
#pragma unroll
    for (int i = 0; i < 4; i++)
#pragma unroll
        for (int j = 0; j < 4; j++) acc[i][j] = {0.f, 0.f, 0.f, 0.f};

    size_t aoff = (size_t)(m0 + wv * 32 + (lane >> 2)) * K + (lane & 3) * 8 + kz;
    size_t boff = (size_t)(n0 + wv * 32 + (lane >> 2)) * K + (lane & 3) * 8 + kz;
    const ushort_t* gA = Ah + aoff;
    const ushort_t* gB = Bh + boff;

    for (int k0 = 0; k0 < Kc; k0 += 32) {
        gld16(gA, &sA[(wv * 32) * 32]);
        gld16(gA + (size_t)16 * K, &sA[(wv * 32 + 16) * 32]);
        gld16(gB, &sB[(wv * 32) * 32]);
        gld16(gB + (size_t)16 * K, &sB[(wv * 32 + 16) * 32]);
        gA += 32; gB += 32;
        __syncthreads();
        half8 ah[4], bh[4];
#pragma unroll
        for (int i = 0; i < 4; i++) ah[i] = *(const half8*)&sA[(wm + i * 16 + fr) * 32 + fq * 8];
#pragma unroll
        for (int j = 0; j < 4; j++) bh[j] = *(const half8*)&sB[(wn + j * 16 + fr) * 32 + fq * 8];
#pragma unroll
        for (int i = 0; i < 4; i++)
#pragma unroll
            for (int j = 0; j < 4; j++)
                acc[i][j] = __builtin_amdgcn_mfma_f32_16x16x32_f16(ah[i], bh[j], acc[i][j], 0, 0, 0);
        __syncthreads();
    }
    float* Cw = C + (size_t)blockIdx.z * (size_t)zpart * (size_t)ldc;
#pragma unroll
    for (int i = 0; i < 4; i++)
#pragma unroll
        for (int j = 0; j < 4; j++)
#pragma unroll
            for (int r = 0; r < 4; r++) {
                int row = m0 + wm + i * 16 + fq * 4 + r;
                int col = n0 + wn + j * 16 + fr;
                if (zpart)
                    Cw[(size_t)row * ldc + col] = acc[i][j][r];
                else
                    atomicAdd(&C[(size_t)row * ldc + col], acc[i][j][r]);
            }
}

// ---------------- grouped f16 MFMA GEMM (MoE): gathered A rows, scattered C rows ----------------
__global__ __launch_bounds__(256) void moe_gemm(const ushort_t* __restrict__ Ab,
                                                const ushort_t* __restrict__ BtAll,
                                                const int* __restrict__ cnt,
                                                const int* __restrict__ ridx_g,
                                                const int* __restrict__ oidx_g,
                                                ushort_t* __restrict__ Cout,
                                                int N, int K, int ebase) {
    int e = ebase + blockIdx.z;
    int nt = cnt[e];
    int mt0 = blockIdx.y * 128;
    if (mt0 >= nt) return;
    const ushort_t* Bt = BtAll + (size_t)blockIdx.z * N * K;
    int n0 = blockIdx.x * 128;
    __shared__ ushort_t Al[4096];
    __shared__ ushort_t Bl[4096];
    __shared__ int ridx[128], oidx[128];
    int tid = threadIdx.x, lane = tid & 63, wv = tid >> 6;
    if (tid < 128) {
        int ii = mt0 + tid;
        bool v = ii < nt;
        ridx[tid] = v ? ridx_g[e * T_TOK + ii] : -1;
        oidx[tid] = v ? oidx_g[e * T_TOK + ii] : -1;
    }
    __syncthreads();
    int wm = (wv & 1) * 64, wn = (wv >> 1) * 64;
    int fr = lane & 15, fq = lane >> 4;
    f32x4 acc[4][4];
#pragma unroll
    for (int i = 0; i < 4; i++)
#pragma unroll
        for (int j = 0; j < 4; j++) acc[i][j] = {0.f, 0.f, 0.f, 0.f};

    int arow = tid >> 1, akoff = (tid & 1) * 16;
    int ra = ridx[arow];
    const ushort_t* asrc = (ra >= 0) ? (Ab + (size_t)ra * K + akoff) : (const ushort_t*)0;
    const ushort_t* gB = Bt + (size_t)(n0 + wv * 32 + (lane >> 2)) * K + (lane & 3) * 8;

    for (int k0 = 0; k0 < K; k0 += 32) {
        uint4 v0 = {0, 0, 0, 0}, v1 = {0, 0, 0, 0};
        if (ra >= 0) {
            v0 = *(const uint4*)(asrc);
            v1 = *(const uint4*)(asrc + 8);
            asrc += 32;
        }
        gld16(gB, &Bl[(wv * 32) * 32]);
        gld16(gB + (size_t)16 * K, &Bl[(wv * 32 + 16) * 32]);
        gB += 32;
        *(uint4*)&Al[arow * 32 + akoff] = v0;
        *(uint4*)&Al[arow * 32 + akoff + 8] = v1;
        __syncthreads();
        half8 af[4], bfr[4];
#pragma unroll
        for (int i = 0; i < 4; i++) af[i] = *(const half8*)&Al[(wm + i * 16 + fr) * 32 + fq * 8];
#pragma unroll
        for (int j = 0; j < 4; j++) bfr[j] = *(const half8*)&Bl[(wn + j * 16 + fr) * 32 + fq * 8];
#pragma unroll
        for (int i = 0; i < 4; i++)
#pragma unroll
            for (int j = 0; j < 4; j++)
                acc[i][j] = __builtin_amdgcn_mfma_f32_16x16x32_f16(af[i], bfr[j], acc[i][j], 0, 0, 0);
        __syncthreads();
    }
#pragma unroll
    for (int i = 0; i < 4; i++)
#pragma unroll
        for (int j = 0; j < 4; j++)
#pragma unroll
            for (int r = 0; r < 4; r++) {
                int lr = wm + i * 16 + fq * 4 + r;
                if (mt0 + lr < nt) {
                    int orow = oidx[lr];
                    Cout[(size_t)orow * N + n0 + wn + j * 16 + fr] = f2h(acc[i][j][r]);
                }
            }
}

// ------- QK RMSNorm + neox RoPE; writes Q and K as f16 planes -------
// Q plane: [t][NH*128]; K plane: [t][NKV*128]
__global__ __launch_bounds__(128) void qk_rope_prep(const float* __restrict__ qkv,
                                                    const float* __restrict__ qw,
                                                    const float* __restrict__ kw,
                                                    const int* __restrict__ positions,
                                                    ushort_t* __restrict__ Qhp,
                                                    ushort_t* __restrict__ Khp) {
    int t = blockIdx.x / (NH + NKV);
    int hh = blockIdx.x % (NH + NKV);
    bool isq = hh < NH;
    const float* x = isq ? qkv + (size_t)t * 3072 + hh * HD
                         : qkv + (size_t)t * 3072 + 2048 + (hh - NH) * HD;
    const float* w = isq ? qw : kw;
    int tid = threadIdx.x;
    float v = x[tid];
    float ss = v * v;
#pragma unroll
    for (int o = 32; o; o >>= 1) ss += __shfl_down(ss, o);
    __shared__ float red[2];
    if ((tid & 63) == 0) red[tid >> 6] = ss;
    __syncthreads();
    float tot = red[0] + red[1];
    float scale = rsqrtf(tot / (float)HD + EPSF);
    float xn = v * scale * w[tid];
    __shared__ float buf[HD];
    buf[tid] = xn;
    __syncthreads();
    if (tid < 64) {
        float x1 = buf[tid], x2 = buf[tid + 64];
        float invf = expf(-((float)tid / 64.0f) * logf(1000000.0f));
        float ang = (float)positions[t] * invf;
        float c = cosf(ang), s = sinf(ang);
        size_t base = isq ? ((size_t)t * (NH * HD) + hh * HD)
                          : ((size_t)t * (NKV * HD) + (hh - NH) * HD);
        ushort_t* oh = isq ? Qhp : Khp;
        oh[base + tid] = f2h(x1 * c - x2 * s);
        oh[base + tid + 64] = f2h(x2 * c + x1 * s);
    }
}

// ---------------- MFMA flash attention: f16 planes, named-register prefetch, KSPLIT=2 ----------------
// grid (qtile, head, z); block z handles k-tiles [kt0, kt1) with own (m,l);
// writes normalized partial O (f32) + per-row (m,l); attn_combine merges.
// LDS 44 KB -> 3 blocks/CU.
#define ATT_SCALE 0.08838834764831845f
__global__ __launch_bounds__(256) void attn_mfma(const ushort_t* __restrict__ Qhp,
                                                 const ushort_t* __restrict__ Khp,
                                                 const ushort_t* __restrict__ Vthp,
                                                 float* __restrict__ Op0,
                                                 float* __restrict__ Op1,
                                                 float* __restrict__ mlb) {
    __shared__ _Float16 sKh[64 * 136];   // K rows, padded stride 136
    __shared__ _Float16 sVh[128 * 72];   // Vt rows [d][krow], padded stride 72
    __shared__ _Float16 sPh[64 * 72];    // P [qrow][krow]

    int qi = blockIdx.x, h = blockIdx.y, z = blockIdx.z;
    int q0 = qi * 64, g = h >> 2;
    int tid = threadIdx.x, lane = tid & 63, wv = tid >> 6;
    int quad = lane >> 4, n16 = lane & 15;
    int nt = qi + 1;
    int halfn = (nt + 1) >> 1;
    int kt0 = z ? halfn : 0;
    int kt1 = z ? nt : halfn;

    // ---- Q A-frags direct from global plane (once per block) ----
    half8 qh[4];
#pragma unroll
    for (int ks = 0; ks < 4; ks++) {
        size_t off = (size_t)(q0 + wv * 16 + n16) * (NH * HD) + h * HD + ks * 32 + quad * 8;
        qh[ks] = *(const half8*)&Qhp[off];
    }

    // NAMED staging registers (rule #20: no arrays)
    uint4 kh0, kh1, kh2, kh3, vv0, vv1, vv2, vv3;

#define STAGE_LOAD(K0)                                                                \
    {                                                                                 \
        size_t bk = (size_t)((K0) + (tid >> 4)) * 512 + g * 128 + (tid & 15) * 8;     \
        kh0 = *(const uint4*)&Khp[bk];                                                \
        kh1 = *(const uint4*)&Khp[bk + 16 * 512];                                     \
        kh2 = *(const uint4*)&Khp[bk + 32 * 512];                                     \
        kh3 = *(const uint4*)&Khp[bk + 48 * 512];                                     \
        size_t bv = (size_t)(g * 128 + (tid >> 3)) * 1024 + (K0) + (tid & 7) * 8;     \
        vv0 = *(const uint4*)&Vthp[bv];                                               \
        vv1 = *(const uint4*)&Vthp[bv + 32 * 1024];                                   \
        vv2 = *(const uint4*)&Vthp[bv + 64 * 1024];                                   \
        vv3 = *(const uint4*)&Vthp[bv + 96 * 1024];                                   \
    }

#define STAGE_WRITE()                                                                 \
    {                                                                                 \
        int wk = (tid >> 4) * 136 + (tid & 15) * 8;                                   \
        *(uint4*)&sKh[wk] = kh0;                                                      \
        *(uint4*)&sKh[wk + 16 * 136] = kh1;                                           \
        *(uint4*)&sKh[wk + 32 * 136] = kh2;                                           \
        *(uint4*)&sKh[wk + 48 * 136] = kh3;                                           \
        int wva = (tid >> 3) * 72 + (tid & 7) * 8;                                    \
        *(uint4*)&sVh[wva] = vv0;                                                     \
        *(uint4*)&sVh[wva + 32 * 72] = vv1;                                           \
        *(uint4*)&sVh[wva + 64 * 72] = vv2;                                           \
        *(uint4*)&sVh[wva + 96 * 72] = vv3;                                           \
    }

    float m_r[4], l_r[4];
#pragma unroll
    for (int r = 0; r < 4; r++) { m_r[r] = -1e30f; l_r[r] = 0.f; }
    f32x4 acc[8];
#pragma unroll
    for (int d = 0; d < 8; d++) acc[d] = {0.f, 0.f, 0.f, 0.f};

    if (kt0 < kt1) {
        STAGE_LOAD(kt0 * 64);
        STAGE_WRITE();
        __syncthreads();

        for (int kt = kt0; kt < kt1; kt++) {
            if (kt + 1 < kt1) STAGE_LOAD((kt + 1) * 64);

            // ---- S = Q K^T : per wave 16q x 64k ----
            f32x4 s[4];
#pragma unroll
            for (int jt = 0; jt < 4; jt++) s[jt] = {0.f, 0.f, 0.f, 0.f};
#pragma unroll
            for (int ks = 0; ks < 4; ks++)
#pragma unroll
                for (int jt = 0; jt < 4; jt++) {
                    half8 bh = *(const half8*)&sKh[(jt * 16 + n16) * 136 + ks * 32 + quad * 8];
                    s[jt] = __builtin_amdgcn_mfma_f32_16x16x32_f16(qh[ks], bh, s[jt], 0, 0, 0);
                }

            // ---- online softmax in C-layout (row = quad*4+r, col = jt*16+n16) ----
            bool last = (kt == qi);
            int lrow_base = wv * 16 + quad * 4;
#pragma unroll
            for (int r = 0; r < 4; r++) {
                float rm = -1e30f;
#pragma unroll
                for (int jt = 0; jt < 4; jt++) {
                    float sv = s[jt][r] * ATT_SCALE;
                    if (last && (jt * 16 + n16 > lrow_base + r)) sv = -1e30f;
                    s[jt][r] = sv;
                    rm = fmaxf(rm, sv);
                }
                rm = fmaxf(rm, __shfl_xor(rm, 1));
                rm = fmaxf(rm, __shfl_xor(rm, 2));
                rm = fmaxf(rm, __shfl_xor(rm, 4));
                rm = fmaxf(rm, __shfl_xor(rm, 8));
                float mo = m_r[r], mn = fmaxf(mo, rm);
                float al = __expf(mo - mn);
                float ls = 0.f;
#pragma unroll
                for (int jt = 0; jt < 4; jt++) {
                    float p = __expf(s[jt][r] - mn);
                    ls += p;
                    sPh[(lrow_base + r) * 72 + jt * 16 + n16] = (_Float16)p;
                }
                ls += __shfl_xor(ls, 1);
                ls += __shfl_xor(ls, 2);
                ls += __shfl_xor(ls, 4);
                ls += __shfl_xor(ls, 8);
                l_r[r] = l_r[r] * al + ls;
                m_r[r] = mn;
#pragma unroll
                for (int dt = 0; dt < 8; dt++) acc[dt][r] *= al;
            }
            __syncthreads();  // P visible; K fully consumed

            // ---- PV: P (A via LDS round-trip) x V (B from transposed Vt) ----
            half8 pah[2];
#pragma unroll
            for (int ks = 0; ks < 2; ks++)
                pah[ks] = *(const half8*)&sPh[(wv * 16 + n16) * 72 + ks * 32 + quad * 8];
#pragma unroll
            for (int dt = 0; dt < 8; dt++)
#pragma unroll
                for (int ks = 0; ks < 2; ks++) {
                    half8 vh = *(const half8*)&sVh[(dt * 16 + n16) * 72 + ks * 32 + quad * 8];
                    acc[dt] = __builtin_amdgcn_mfma_f32_16x16x32_f16(pah[ks], vh, acc[dt], 0, 0, 0);
                }
            __syncthreads();  // V and P consumed

            if (kt + 1 < kt1) {
                STAGE_WRITE();   // vmcnt wait on prefetched regs lands here
                __syncthreads();
            }
        }
    }

    // ---- epilogue: normalized partial O (f32) + per-row (m, l) ----
    float* Op = z ? Op1 : Op0;
#pragma unroll
    for (int r = 0; r < 4; r++) {
        float inv = (l_r[r] > 0.f) ? 1.f / l_r[r] : 0.f;
        int row = q0 + wv * 16 + quad * 4 + r;
#pragma unroll
        for (int dt = 0; dt < 8; dt++)
            Op[(size_t)row * 2048 + h * HD + dt * 16 + n16] = acc[dt][r] * inv;
        if (n16 == 0) {
            size_t mi = ((size_t)(z * T_TOK + row) * NH + h) * 2;
            mlb[mi] = m_r[r];
            mlb[mi + 1] = l_r[r];
        }
    }
#undef STAGE_LOAD
#undef STAGE_WRITE
}

// ---------------- merge the two k-split partials -> o f16 plane ----------------
__global__ __launch_bounds__(256) void attn_combine(const float* __restrict__ Op0,
                                                    const float* __restrict__ Op1,
                                                    const float* __restrict__ mlb,
                                                    ushort_t* __restrict__ ohp) {
    int idx = blockIdx.x * 256 + threadIdx.x;
    int t = idx >> 11;
    int h = (idx >> 7) & 15;
    size_t mi0 = ((size_t)t * NH + h) * 2;
    size_t mi1 = ((size_t)(T_TOK + t) * NH + h) * 2;
    float m0 = mlb[mi0], l0 = mlb[mi0 + 1];
    float m1 = mlb[mi1], l1 = mlb[mi1 + 1];
    float M = fmaxf(m0, m1);
    float w0 = l0 * __expf(m0 - M);
    float w1 = l1 * __expf(m1 - M);
    ohp[idx] = f2h((w0 * Op0[idx] + w1 * Op1[idx]) / (w0 + w1));
}

// ---------------- router: softmax over 8 experts, top-2, bucket by expert ----------------
__global__ __launch_bounds__(256) void router(const float* __restrict__ h2,
                                              const float* __restrict__ gate_w,
                                              int* __restrict__ cnt,
                                              int* __restrict__ btok,
                                              int* __restrict__ bslot,
                                              float* __restrict__ wslot) {
    int t = blockIdx.x, tid = threadIdx.x;
    int e = tid & 7, c = tid >> 3;
    float part = 0.f;
    for (int i = 0; i < 64; i++) {
        int hh = c * 64 + i;
        part += h2[(size_t)t * H_DIM + hh] * gate_w[hh * NEXP + e];
    }
    __shared__ float red[256];
    red[tid] = part;
    __syncthreads();
    for (int s = 128; s >= 8; s >>= 1) {
        if (tid < s) red[tid] += red[tid + s];
        __syncthreads();
    }
    if (tid == 0) {
        float mx = -1e30f;
        for (int i = 0; i < NEXP; i++) mx = fmaxf(mx, red[i]);
        float p[NEXP];
        for (int i = 0; i < NEXP; i++) p[i] = expf(red[i] - mx);
        int i1 = 0;
        for (int i = 1; i < NEXP; i++) if (p[i] > p[i1]) i1 = i;
        int i2 = (i1 == 0) ? 1 : 0;
        for (int i = 0; i < NEXP; i++) if (i != i1 && p[i] > p[i2]) i2 = i;
        float denom = p[i1] + p[i2];
        wslot[2 * t] = p[i1] / denom;
        wslot[2 * t + 1] = p[i2] / denom;
        int pos = atomicAdd(&cnt[i1], 1);
        btok[i1 * T_TOK + pos] = t; bslot[i1 * T_TOK + pos] = 2 * t;
        pos = atomicAdd(&cnt[i2], 1);
        btok[i2 * T_TOK + pos] = t; bslot[i2 * T_TOK + pos] = 2 * t + 1;
    }
}

// ---------------- SwiGLU: gu f16 [2048][1536] -> act f16 [2048][768] ----------------
__global__ __launch_bounds__(256) void swiglu(const ushort_t* __restrict__ gu,
                                              ushort_t* __restrict__ act) {
    int idx = blockIdx.x * 256 + threadIdx.x;
    int s = idx / I_DIM, i = idx - s * I_DIM;
    float g = h2f_(gu[(size_t)s * (2 * I_DIM) + i]);
    float u = h2f_(gu[(size_t)s * (2 * I_DIM) + I_DIM + i]);
    act[idx] = f2h(g / (1.f + expf(-g)) * u);
}

// ---------------- combine: out[t] = w0*dbuf[2t] + w1*dbuf[2t+1] ----------------
__global__ __launch_bounds__(256) void combine(const ushort_t* __restrict__ dbuf,
                                               const float* __restrict__ wslot,
                                               float* __restrict__ out) {
    int idx = blockIdx.x * 256 + threadIdx.x;
    int t = idx >> 11;
    out[idx] = wslot[2 * t] * h2f_(dbuf[(size_t)(2 * t) * H_DIM + (idx & 2047)]) +
               wslot[2 * t + 1] * h2f_(dbuf[(size_t)(2 * t + 1) * H_DIM + (idx & 2047)]);
}

extern "C" void kernel_launch(void* const* d_in, const int* in_sizes, int n_in,
                              void* d_out, int out_size, void* d_ws, size_t ws_size,
                              hipStream_t stream) {
    const int* positions = (const int*)d_in[0];
    const float* hs = (const float*)d_in[1];
    const float* resid = (const float*)d_in[2];
    const float* w_qkv = (const float*)d_in[3];
    const float* w_o = (const float*)d_in[4];
    const float* q_norm_w = (const float*)d_in[5];
    const float* k_norm_w = (const float*)d_in[6];
    const float* ln1_w = (const float*)d_in[7];
    const float* ln2_w = (const float*)d_in[8];
    const float* gate_w = (const float*)d_in[9];
    const float* w_gu = (const float*)d_in[10];
    const float* w_dn = (const float*)d_in[11];

    float* out = (float*)d_out;
    float* res2 = out + (size_t)T_TOK * H_DIM;

    const size_t MB = 1ull << 20;
    char* W = (char*)d_ws;
    // ---- per-step disjointness-audited layout ----
    // 0-8:   res1 (live 2-8) | gub 0-6 (live 10-11) | dbuf 0-8 (live 12-13)
    float*    res1   = (float*)(W + 0);
    ushort_t* gub    = (ushort_t*)(W + 0);
    ushort_t* dbuf   = (ushort_t*)(W + 0);
    // 8-16:  h1h 8-12 (live 2-3) | ohp 8-12 (live 5.5-7) | h2h 8-12 (live 8-10) | actb 12-15 (live 11-12)
    ushort_t* h1h    = (ushort_t*)(W + 8 * MB);
    ushort_t* ohp    = (ushort_t*)(W + 8 * MB);
    ushort_t* h2h    = (ushort_t*)(W + 8 * MB);
    ushort_t* actb   = (ushort_t*)(W + 12 * MB);
    // 16-28: qkvf 16-28 (live 3-4) | attnO0 16-24 + ml 24-24.25 (live 5-5.5)
    //        | wTh_o 16-24 (live 6-7) | h2f 16-24 (live 8-9) | wTmoe 16-41.2 (live 10-12)
    float*    qkvf   = (float*)(W + 16 * MB);
    float*    attnO0 = (float*)(W + 16 * MB);
    float*    attnml = (float*)(W + 24 * MB);
    ushort_t* wTh_o  = (ushort_t*)(W + 16 * MB);
    float*    h2f    = (float*)(W + 16 * MB);
    ushort_t* wTmoe  = (ushort_t*)(W + 16 * MB);
    // 28-40: wT_q 28-34 (live step 3) | attn planes: Qhp 28-32, Khp 32-33, Vthp 33-34 (live 4-5)
    ushort_t* wTh_q  = (ushort_t*)(W + 28 * MB);
    ushort_t* Qhp    = (ushort_t*)(W + 28 * MB);  // 4 MiB
    ushort_t* Khp    = (ushort_t*)(W + 32 * MB);  // 1 MiB
    ushort_t* Vthp   = (ushort_t*)(W + 33 * MB);  // 1 MiB
    // 32-48: oprojf (live 7-8) | 40-48: attnO1 (live 5-5.5; dead before oprojf written)
    float*    oprojf = (float*)(W + 32 * MB);
    float*    attnO1 = (float*)(W + 40 * MB);
    // 48+:   buckets (live 9-13)
    int*      cnt    = (int*)(W + 48 * MB);
    int*      btok   = cnt + 16;
    int*      bslot  = btok + NEXP * T_TOK;
    float*    wslot  = (float*)(bslot + NEXP * T_TOK);

    // 1+2. res1 = hs + resid; h1 = rms(res1)*ln1 f16
    add_rms1<<<T_TOK, 256, 0, stream>>>(hs, resid, ln1_w, res1, h1h);
    // 3. qkv = h1 @ w_qkv in two N-chunks of 1536, split-K=4 (atomic f32)
    hipMemsetAsync(qkvf, 0, (size_t)T_TOK * 3072 * 4, stream);
    for (int c = 0; c < 2; c++) {
        castT_h<<<dim3(1536 / 32, 2048 / 32, 1), 256, 0, stream>>>(
            w_qkv + c * 1536, wTh_q, 2048, 3072, 0);
        gemm_f16<<<dim3(1536 / 128, 1024 / 128, 4), 256, 0, stream>>>(
            h1h, wTh_q, qkvf + c * 1536, 3072, 2048, 0);
    }
    // 4. q/k RMSNorm + RoPE -> Q/K f16 planes; V transpose -> Vt plane
    qk_rope_prep<<<T_TOK * (NH + NKV), 128, 0, stream>>>(qkvf, q_norm_w, k_norm_w, positions,
                                                         Qhp, Khp);
    prep_vt<<<dim3(HD / 32, T_TOK / 32, NKV), 256, 0, stream>>>(qkvf, Vthp);
    // 5. MFMA flash attention, k-split=2 -> partial O (16-24, 40-48) + ml (24MB)
    attn_mfma<<<dim3(T_TOK / 64, NH, 2), 256, 0, stream>>>(Qhp, Khp, Vthp,
                                                           attnO0, attnO1, attnml);
    // 5.5. merge partials -> ohp f16 plane at 8-12
    attn_combine<<<(T_TOK * H_DIM) / 256, 256, 0, stream>>>(attnO0, attnO1, attnml, ohp);
    // 6. w_o transpose -> 16-24 (attn partials dead)
    castT_h<<<dim3(2048 / 32, 2048 / 32, 1), 256, 0, stream>>>(w_o, wTh_o, 2048, 2048, 0);
    // 7. oproj = attn_out @ w_o, split-K=2 partial mode -> 32-48
    gemm_f16<<<dim3(2048 / 128, 1024 / 128, 2), 256, 0, stream>>>(
        ohp, wTh_o, oprojf, 2048, 2048, 1024);
    // 8. res2 = oproj0 + oproj1 + res1 (-> d_out); h2 f32 (16-24) + f16 (8-12)
    add_rms2<<<T_TOK, 256, 0, stream>>>(oprojf, oprojf + (size_t)1024 * 2048, res1, ln2_w,
                                        res2, h2f, h2h);
    // 9. router (f32 logits)
    hipMemsetAsync(cnt, 0, NEXP * sizeof(int), stream);
    router<<<T_TOK, 256, 0, stream>>>(h2f, gate_w, cnt, btok, bslot, wslot);
    // 10. MoE gate_up in 2 chunks of 4 experts (weights at 16+; gub at 0)
    for (int c = 0; c < 2; c++) {
        castT_h<<<dim3(1536 / 32, 2048 / 32, 4), 256, 0, stream>>>(
            w_gu + (size_t)c * 4 * 2048 * 1536, wTmoe, 2048, 1536, (size_t)2048 * 1536);
        moe_gemm<<<dim3(1536 / 128, 8, 4), 256, 0, stream>>>(
            h2h, wTmoe, cnt, btok, bslot, gub, 1536, 2048, c * 4);
    }
    // 11. SwiGLU: gub (0-6) -> actb (12-15)
    swiglu<<<(2048 * I_DIM) / 256, 256, 0, stream>>>(gub, actb);
    // 12. MoE down, all 8 experts (weights 16-40; actb 12-15; dbuf 0-8)
    castT_h<<<dim3(2048 / 32, 768 / 32, 8), 256, 0, stream>>>(
        w_dn, wTmoe, 768, 2048, (size_t)768 * 2048);
    moe_gemm<<<dim3(2048 / 128, 8, 8), 256, 0, stream>>>(
        actb, wTmoe, cnt, bslot, bslot, dbuf, 2048, 768, 0);
    // 13. weighted combine
    combine<<<(T_TOK * H_DIM) / 256, 256, 0, stream>>>(dbuf, wslot, out);
}